// Round 12
// baseline (290.502 us; speedup 1.0000x reference)
//
#include <hip/hip_runtime.h>
#include <hip/hip_bf16.h>
#include <stdint.h>

#define B_D   384
#define B_E   2048
#define TOPK  50
#define LN_EPS 1e-5f
#define NKS   18            // logical K-steps of 64 (K' = 1152 = 3*384)
#define NKP   12            // physical packed K-steps (hi + lo, dedup'd)
#define NU    36            // pipeline units = K-halves of 32
#define FIX_WINDOW 2e-4f

typedef short bf16x8 __attribute__((ext_vector_type(8)));
typedef float f32x4  __attribute__((ext_vector_type(4)));

// ---------------- wave helpers (wave64) ----------------
__device__ __forceinline__ float wave_sum_f(float v) {
#pragma unroll
    for (int d = 1; d < 64; d <<= 1) v += __shfl_xor(v, d, 64);
    return v;
}
__device__ __forceinline__ int wave_sum_i(int v) {
#pragma unroll
    for (int d = 1; d < 64; d <<= 1) v += __shfl_xor(v, d, 64);
    return v;
}
__device__ __forceinline__ float wave_max_f(float v) {
#pragma unroll
    for (int d = 1; d < 64; d <<= 1) v = fmaxf(v, __shfl_xor(v, d, 64));
    return v;
}

__device__ __forceinline__ ushort f2bf_hi(float v) {
    __hip_bfloat16 b = __float2bfloat16(v);
    return *(ushort*)&b;
}
__device__ __forceinline__ ushort f2bf_lo(float v) {
    __hip_bfloat16 b = __float2bfloat16(v);
    float rem = v - __bfloat162float(b);
    __hip_bfloat16 l = __float2bfloat16(rem);
    return *(ushort*)&l;
}

__device__ __forceinline__ void llds16(const void* g, void* l) {
    __builtin_amdgcn_global_load_lds((const __attribute__((address_space(1))) void*)g,
                                     (__attribute__((address_space(3))) void*)l, 16, 0, 0);
}

// ---------------- fused pack: A (mt=0..63) and B (y=64..71) tiles ----------------
__global__ __launch_bounds__(256) void pack_AB(
    const float* __restrict__ x, const float* __restrict__ We,
    ushort* __restrict__ Ap, ushort* __restrict__ Bp, int* __restrict__ cntr)
{
    const int ks = blockIdx.x, yb = blockIdx.y, t = threadIdx.x;
    if (cntr && t == 0 && ks == 0 && yb == 0) *cntr = 0;
    if (yb < 64) {
        const int mt = yb;
#pragma unroll
        for (int q = 0; q < 8; ++q) {
            const int s = q * 256 + t;          // 0..2047
            const int m = s & 255, kg = s >> 8;
            const int kp = ks * 64 + kg * 8;    // 0..767
            const int hi = (kp < 384);
            const int ksrc = hi ? kp : kp - 384;
            const float* src = x + (size_t)(mt * 256 + m) * B_D + ksrc;
            float4 v0 = *(const float4*)src;
            float4 v1 = *(const float4*)(src + 4);
            float vv[8] = {v0.x, v0.y, v0.z, v0.w, v1.x, v1.y, v1.z, v1.w};
            ushort o[8];
#pragma unroll
            for (int e = 0; e < 8; ++e)
                o[e] = hi ? f2bf_hi(vv[e]) : f2bf_lo(vv[e]);
            *(uint4*)(Ap + ((size_t)(mt * NKP + ks) * 2048 + s) * 8) = *(uint4*)o;
        }
    } else {
        const int nt = yb - 64;
#pragma unroll
        for (int q = 0; q < 8; ++q) {
            const int s = q * 256 + t;
            const int nl = s & 255, kg = s >> 8;
            const int kp = ks * 64 + kg * 8;
            const int hi = (kp < 384);
            const int ksrc = hi ? kp : kp - 384;
            const int ng = nt * 256 + nl;
            ushort o[8];
#pragma unroll
            for (int e = 0; e < 8; ++e) {
                float v = We[(size_t)(ksrc + e) * B_E + ng];
                o[e] = hi ? f2bf_hi(v) : f2bf_lo(v);
            }
            *(uint4*)(Bp + ((size_t)(nt * NKP + ks) * 2048 + s) * 8) = *(uint4*)o;
        }
    }
}

// ---------------- MFMA encoder GEMM, 256x256 tile, 3-slot counted-vmcnt pipeline ----------------
// Unit u (0..35): K-tile ls=u>>1, k-half h=u&1 (ascending k -> bit-identical acc order
// vs the verified 2-phase kernel). Slot rotation mod 3; issue(u+2) AFTER the unit-u
// barrier (slot (u+2)%3 last read by unit u-1, whose ds_reads completed pre-barrier).
// Gate: per-wave s_waitcnt vmcnt(4) (u landed; u+1 in flight) + raw s_barrier.
__global__ __launch_bounds__(512, 2) void enc_mfma256_p(
    const ushort* __restrict__ Ap, const ushort* __restrict__ Bp,
    const float* __restrict__ be, float* __restrict__ y)
{
    __shared__ __align__(16) ushort As[3][8192];   // 3 x 16 KB
    __shared__ __align__(16) ushort Bs[3][8192];   // 3 x 16 KB
    const int t = threadIdx.x, lane = t & 63, w = t >> 6;
    const int wr = w >> 2, wc = w & 3;
    const int gid = blockIdx.x;
    const int swz = (gid & 7) * 64 + (gid >> 3);   // XCD-aware (512 % 8 == 0, bijective)
    const int nt = swz & 7, mt = swz >> 3;
    const ushort* gA = Ap + (size_t)mt * NKP * 16384;
    const ushort* gB = Bp + (size_t)nt * NKP * 16384;

    f32x4 acc[8][4];
#pragma unroll
    for (int i = 0; i < 8; ++i)
#pragma unroll
        for (int j = 0; j < 4; ++j)
#pragma unroll
            for (int r = 0; r < 4; ++r) acc[i][j][r] = 0.f;

    const int l15 = lane & 15, l4 = lane >> 4;

#define ISSUE_U(u_)                                                             \
    {                                                                           \
        const int uu = (u_);                                                    \
        const int lsv = uu >> 1, hh = uu & 1, sl = uu % 3;                      \
        const int ksA = (lsv < 6) ? lsv : lsv - 6;                              \
        const int ksB = (lsv < 12) ? lsv : lsv - 12;                            \
        const ushort* as_ = gA + (size_t)ksA * 16384 + hh * 8192 + t * 8;       \
        const ushort* bs_ = gB + (size_t)ksB * 16384 + hh * 8192 + t * 8;       \
        llds16(as_,        &As[sl][t * 8]);                                     \
        llds16(as_ + 4096, &As[sl][4096 + t * 8]);                              \
        llds16(bs_,        &Bs[sl][t * 8]);                                     \
        llds16(bs_ + 4096, &Bs[sl][4096 + t * 8]);                              \
    }

    ISSUE_U(0);
    ISSUE_U(1);

    for (int u = 0; u < NU; ++u) {
        if (u < NU - 1) asm volatile("s_waitcnt vmcnt(4)" ::: "memory");
        else            asm volatile("s_waitcnt vmcnt(0)" ::: "memory");
        __builtin_amdgcn_sched_barrier(0);
        __builtin_amdgcn_s_barrier();
        __builtin_amdgcn_sched_barrier(0);
        if (u + 2 < NU) ISSUE_U(u + 2);
        const int sl = u % 3;
        bf16x8 bfr[4], af0[4], af1[4];
#pragma unroll
        for (int j = 0; j < 4; ++j)
            bfr[j] = *(const bf16x8*)&Bs[sl][(l4 * 256 + wc * 64 + j * 16 + l15) * 8];
#pragma unroll
        for (int i = 0; i < 4; ++i)
            af0[i] = *(const bf16x8*)&As[sl][(l4 * 256 + wr * 128 + i * 16 + l15) * 8];
        __builtin_amdgcn_s_setprio(1);
#pragma unroll
        for (int i = 0; i < 4; ++i)
#pragma unroll
            for (int j = 0; j < 4; ++j)
                acc[i][j] = __builtin_amdgcn_mfma_f32_16x16x32_bf16(af0[i], bfr[j], acc[i][j], 0, 0, 0);
        __builtin_amdgcn_s_setprio(0);
#pragma unroll
        for (int i = 0; i < 4; ++i)
            af1[i] = *(const bf16x8*)&As[sl][(l4 * 256 + wr * 128 + (4 + i) * 16 + l15) * 8];
        __builtin_amdgcn_s_setprio(1);
#pragma unroll
        for (int i = 0; i < 4; ++i)
#pragma unroll
            for (int j = 0; j < 4; ++j)
                acc[4 + i][j] = __builtin_amdgcn_mfma_f32_16x16x32_bf16(af1[i], bfr[j], acc[4 + i][j], 0, 0, 0);
        __builtin_amdgcn_s_setprio(0);
    }
#undef ISSUE_U

    float bev[4];
#pragma unroll
    for (int j = 0; j < 4; ++j) bev[j] = be[nt * 256 + wc * 64 + j * 16 + l15];
#pragma unroll
    for (int i = 0; i < 8; ++i)
#pragma unroll
        for (int j = 0; j < 4; ++j)
#pragma unroll
            for (int r = 0; r < 4; ++r) {
                const int row = mt * 256 + wr * 128 + i * 16 + l4 * 4 + r;
                const int col = nt * 256 + wc * 64 + j * 16 + l15;
                y[(size_t)row * B_E + col] = acc[i][j][r] + bev[j];
            }
}

// ---------------- fp32 fallback GEMM ----------------
__global__ __launch_bounds__(256) void enc_gemm_f32(
    const float* __restrict__ x, const float* __restrict__ We,
    const float* __restrict__ be, float* __restrict__ y)
{
    __shared__ float As[8][128];
    __shared__ float Bs[8][128];
    const int t  = threadIdx.x;
    const int m0 = blockIdx.y * 128;
    const int n0 = blockIdx.x * 128;
    const int tx = t & 15, ty = t >> 4;
    const int la_m = t >> 1, la_k = (t & 1) * 4;
    const int lb_k = t >> 5, lb_c = (t & 31) * 4;

    float acc[8][8];
#pragma unroll
    for (int i = 0; i < 8; ++i)
#pragma unroll
        for (int j = 0; j < 8; ++j) acc[i][j] = 0.f;

    for (int k0 = 0; k0 < B_D; k0 += 8) {
        float4 a = *(const float4*)&x[(size_t)(m0 + la_m) * B_D + k0 + la_k];
        float4 b = *(const float4*)&We[(size_t)(k0 + lb_k) * B_E + n0 + lb_c];
        __syncthreads();
        As[la_k + 0][la_m] = a.x;
        As[la_k + 1][la_m] = a.y;
        As[la_k + 2][la_m] = a.z;
        As[la_k + 3][la_m] = a.w;
        *(float4*)&Bs[lb_k][lb_c] = b;
        __syncthreads();
#pragma unroll
        for (int kk = 0; kk < 8; ++kk) {
            float4 a0 = *(const float4*)&As[kk][ty * 4];
            float4 a1 = *(const float4*)&As[kk][ty * 4 + 64];
            float4 b0 = *(const float4*)&Bs[kk][tx * 4];
            float4 b1 = *(const float4*)&Bs[kk][tx * 4 + 64];
            float av[8] = {a0.x,a0.y,a0.z,a0.w,a1.x,a1.y,a1.z,a1.w};
            float bv[8] = {b0.x,b0.y,b0.z,b0.w,b1.x,b1.y,b1.z,b1.w};
#pragma unroll
            for (int i = 0; i < 8; ++i)
#pragma unroll
                for (int j = 0; j < 8; ++j)
                    acc[i][j] = fmaf(av[i], bv[j], acc[i][j]);
        }
    }
    float4 beL = *(const float4*)&be[n0 + tx * 4];
    float4 beH = *(const float4*)&be[n0 + 64 + tx * 4];
    float bl[8] = {beL.x,beL.y,beL.z,beL.w,beH.x,beH.y,beH.z,beH.w};
#pragma unroll
    for (int i = 0; i < 8; ++i) {
        int row = m0 + ty * 4 + (i & 3) + (i >> 2) * 64;
        float4 o0 = {acc[i][0]+bl[0], acc[i][1]+bl[1], acc[i][2]+bl[2], acc[i][3]+bl[3]};
        float4 o1 = {acc[i][4]+bl[4], acc[i][5]+bl[5], acc[i][6]+bl[6], acc[i][7]+bl[7]};
        *(float4*)&y[(size_t)row * B_E + n0 + tx * 4]      = o0;
        *(float4*)&y[(size_t)row * B_E + n0 + 64 + tx * 4] = o1;
    }
}

// ------- shared per-row LN -> relu -> exact top-50; returns ambiguity flag -------
__device__ __forceinline__ int ln_topk_row(
    float (&h)[32], int lane, const float* __restrict__ g1, const float* __restrict__ b1,
    float* __restrict__ row, int* __restrict__ IwR, float* __restrict__ VwR,
    float* __restrict__ ldsv, int* __restrict__ ldsi)
{
    float s = 0.f;
#pragma unroll
    for (int j = 0; j < 32; ++j) s += h[j];
    s = wave_sum_f(s);
    const float mu = s * (1.f / B_E);
    float ss = 0.f;
#pragma unroll
    for (int j = 0; j < 32; ++j) { float d = h[j] - mu; ss += d * d; }
    ss = wave_sum_f(ss);
    const float rstd = rsqrtf(ss * (1.f / B_E) + LN_EPS);
#pragma unroll
    for (int q = 0; q < 8; ++q) {
        float4 g  = *(const float4*)&g1[q * 256 + lane * 4];
        float4 bb = *(const float4*)&b1[q * 256 + lane * 4];
        float gg[4]  = {g.x,g.y,g.z,g.w};
        float bbv[4] = {bb.x,bb.y,bb.z,bb.w};
#pragma unroll
        for (int i = 0; i < 4; ++i) {
            int j = q*4+i;
            h[j] = fmaxf(fmaf((h[j] - mu) * rstd, gg[i], bbv[i]), 0.f);
        }
    }
    float mx = h[0];
#pragma unroll
    for (int j = 1; j < 32; ++j) mx = fmaxf(mx, h[j]);
    mx = wave_max_f(mx);

    // Phase 1: value-space bisection; invariant count(>=vlo) = cl >= TOPK.
    float vlo = 0.f, vhi = __uint_as_float(__float_as_uint(mx) + 1u);
    int cl = 2048;
    bool window = false;
    for (int it = 0; it < 20; ++it) {
        float mid = 0.5f * (vlo + vhi);
        if (it == 0 && 2.2f > vlo && 2.2f < vhi) mid = 2.2f;
        if (!(mid > vlo && mid < vhi)) break;
        int c = 0;
#pragma unroll
        for (int j = 0; j < 32; ++j)
            c += (int)__popcll(__ballot(h[j] >= mid));
        if (c >= TOPK) { vlo = mid; cl = c; if (c <= 64) { window = true; break; } }
        else vhi = mid;
    }
    unsigned lo = __float_as_uint(vlo);
    if (!window) {
        unsigned hi = __float_as_uint(vhi);
        while (hi - lo > 1u) {
            const unsigned mid = lo + ((hi - lo) >> 1);
            const float mf = __uint_as_float(mid);
            int c = 0;
#pragma unroll
            for (int j = 0; j < 32; ++j)
                c += (int)__popcll(__ballot(h[j] >= mf));
            if (c >= TOPK) { lo = mid; cl = c; if (c <= 64) break; }
            else hi = mid;
        }
    }
    const float T0 = __uint_as_float(lo);

    unsigned selmask = 0u;
    int flag = 0;
    bool fastSel = (cl <= 64 && T0 > 0.f);

    if (fastSel) {
        ldsv[lane] = -1.f;
        ldsi[lane] = 1 << 20;
        asm volatile("s_waitcnt lgkmcnt(0)" ::: "memory");
        int base = 0;
#pragma unroll
        for (int j = 0; j < 32; ++j) {
            const bool p = (h[j] >= T0);
            const unsigned long long m = __ballot(p);
            if (p) {
                const int pos = base + (int)__popcll(m & ((1ull << lane) - 1ull));
                ldsv[pos] = h[j];
                ldsi[pos] = (j >> 2) * 256 + lane * 4 + (j & 3);
            }
            base += (int)__popcll(m);
        }
        asm volatile("s_waitcnt lgkmcnt(0)" ::: "memory");
        float sv = ldsv[lane];
        int   si = ldsi[lane];
#pragma unroll
        for (int k = 2; k <= 64; k <<= 1) {
#pragma unroll
            for (int jj = k >> 1; jj > 0; jj >>= 1) {
                const float ov = __shfl_xor(sv, jj, 64);
                const int   oi = __shfl_xor(si, jj, 64);
                const bool dirUp = ((lane & k) == 0);
                const bool lower = ((lane & jj) == 0);
                const bool mineBefore = (sv > ov) || (sv == ov && si < oi);
                const bool keep = (lower == dirUp) ? mineBefore : !mineBefore;
                if (!keep) { sv = ov; si = oi; }
            }
        }
        const float T    = __shfl(sv, TOPK - 1, 64);
        const int   idxT = __shfl(si, TOPK - 1, 64);
        float v51;
        if (cl > TOPK) {
            v51 = __shfl(sv, TOPK, 64);
        } else {
            float bb = -1.f;
#pragma unroll
            for (int j = 0; j < 32; ++j) bb = (h[j] < T0) ? fmaxf(bb, h[j]) : bb;
            v51 = wave_max_f(bb);
        }
        flag = (T - v51 < FIX_WINDOW) ? 1 : 0;
#pragma unroll
        for (int j = 0; j < 32; ++j) {
            const int e = (j >> 2) * 256 + lane * 4 + (j & 3);
            if (h[j] > T || (h[j] == T && e <= idxT)) selmask |= (1u << j);
        }
        if (lane < TOPK) { IwR[lane] = si; VwR[lane] = sv; }
    } else {
        const float T = T0;
        int cgt = 0, ceq = 0;
        float below = -1.f;
#pragma unroll
        for (int j = 0; j < 32; ++j) {
            cgt += (h[j] > T); ceq += (h[j] == T);
            if (h[j] < T) below = fmaxf(below, h[j]);
        }
        const int cgt_t = wave_sum_i(cgt);
        const int ceq_t = wave_sum_i(ceq);
        below = wave_max_f(below);
        const int need = TOPK - cgt_t;

        if (cgt_t + ceq_t == TOPK) {
#pragma unroll
            for (int j = 0; j < 32; ++j) if (h[j] >= T) selmask |= (1u << j);
        } else {
            int base = 0;
            for (int q = 0; q < 8; ++q) {
                int tc = 0;
#pragma unroll
                for (int i = 0; i < 4; ++i) tc += (h[q*4+i] == T);
                int ip = tc;
#pragma unroll
                for (int d = 1; d < 64; d <<= 1) {
                    int o = __shfl_up(ip, d, 64);
                    if (lane >= d) ip += o;
                }
                int rk  = base + ip - tc;
                int tot = __shfl(ip, 63, 64);
#pragma unroll
                for (int i = 0; i < 4; ++i) {
                    int j = q*4+i;
                    if (h[j] > T) selmask |= (1u << j);
                    else if (h[j] == T) { if (rk < need) selmask |= (1u << j); rk++; }
                }
                base += tot;
            }
        }
        if (T > 0.f) {
            if (cgt_t + ceq_t != TOPK && ceq_t > need) flag = 1;
            else if (T - below < FIX_WINDOW) flag = 1;
        }
        const int myc = __popc(selmask);
        int ip = myc;
#pragma unroll
        for (int d = 1; d < 64; d <<= 1) {
            int o = __shfl_up(ip, d, 64);
            if (lane >= d) ip += o;
        }
        int pos = ip - myc;
        for (int j = 0; j < 32; ++j) {
            if ((selmask >> j) & 1u) {
                int e = (j >> 2) * 256 + lane * 4 + (j & 3);
                IwR[pos] = e;
                VwR[pos] = h[j];
                pos++;
            }
        }
    }

#pragma unroll
    for (int q = 0; q < 8; ++q) {
        float4 o;
        o.x = ((selmask >> (q*4+0)) & 1u) ? h[q*4+0] : 0.f;
        o.y = ((selmask >> (q*4+1)) & 1u) ? h[q*4+1] : 0.f;
        o.z = ((selmask >> (q*4+2)) & 1u) ? h[q*4+2] : 0.f;
        o.w = ((selmask >> (q*4+3)) & 1u) ? h[q*4+3] : 0.f;
        *(float4*)&row[q * 256 + lane * 4] = o;
    }
    return flag;
}

// ------- topk (blocks 0..nTopk-1) fused with pack_W (blocks nTopk..nTopk+1023) -------
__global__ __launch_bounds__(256) void topk_packW(
    float* __restrict__ y, const float* __restrict__ g1, const float* __restrict__ b1,
    int* __restrict__ Iw, float* __restrict__ Vw,
    int* __restrict__ rowlist, int* __restrict__ cntr,
    const float* __restrict__ Wd, const float* __restrict__ Wb, uint* __restrict__ Wp,
    int nTopk)
{
    __shared__ float ldsv[4][64];
    __shared__ int   ldsi[4][64];
    const int bid = blockIdx.x;
    const int t = threadIdx.x;
    if (bid >= nTopk) {
        const int e = (bid - nTopk) * 2 + (t >> 7);
        const int tt = t & 127;
#pragma unroll
        for (int j = 0; j < 3; ++j) {
            const int c = tt + 128 * j;
            const ushort d = f2bf_hi(Wd[(size_t)e * B_D + c]);
            const ushort b = f2bf_hi(Wb[(size_t)e * B_D + c]);
            Wp[(size_t)e * B_D + c] = ((uint)b << 16) | (uint)d;
        }
        return;
    }
    const int lane = t & 63;
    const int w = t >> 6;
    const int r = bid * 4 + w;
    float* row = y + (size_t)r * B_E;
    float h[32];
#pragma unroll
    for (int q = 0; q < 8; ++q) {
        float4 v = *(const float4*)&row[q * 256 + lane * 4];
        h[q*4+0] = v.x; h[q*4+1] = v.y; h[q*4+2] = v.z; h[q*4+3] = v.w;
    }
    int flag = ln_topk_row(h, lane, g1, b1, row, Iw + r * TOPK, Vw + r * TOPK,
                           ldsv[w], ldsi[w]);
    if (rowlist && lane == 0 && flag) {
        int p = atomicAdd(cntr, 1);
        rowlist[p] = r;
    }
}

// ------- fixup phase 1: exact fp32 recompute of flagged rows (pre-LN y) -------
__global__ __launch_bounds__(256) void fixup_recompute(
    const float* __restrict__ x, const float* __restrict__ We, const float* __restrict__ be,
    float* __restrict__ y, const int* __restrict__ rowlist, const int* __restrict__ cntr)
{
    const int nflag = *cntr;
    const int rb = blockIdx.y * 8;
    if (rb >= nflag) return;
    const int nact = min(nflag - rb, 8);
    const int t = threadIdx.x;

    __shared__ float xs[8][B_D];
    __shared__ int   rIdx[8];
    if (t < 8) rIdx[t] = (t < nact) ? rowlist[rb + t] : -1;
    __syncthreads();
#pragma unroll
    for (int i = 0; i < 8; ++i) {
        if (i < nact) {
            const float* src = x + (size_t)rIdx[i] * B_D;
            for (int j = t; j < B_D; j += 256) xs[i][j] = src[j];
        } else {
            for (int j = t; j < B_D; j += 256) xs[i][j] = 0.f;
        }
    }
    __syncthreads();

    const int c = blockIdx.x * 256 + t;
    const float bc = be[c];
    float acc[8];
#pragma unroll
    for (int i = 0; i < 8; ++i) acc[i] = bc;
#pragma unroll 4
    for (int k = 0; k < B_D; ++k) {
        const float w = We[(size_t)k * B_E + c];
#pragma unroll
        for (int i = 0; i < 8; ++i) acc[i] = fmaf(xs[i][k], w, acc[i]);
    }
#pragma unroll
    for (int i = 0; i < 8; ++i)
        if (i < nact) y[(size_t)rIdx[i] * B_E + c] = acc[i];
}

// ------- fixup phase 2: redo LN+topk on flagged rows (rowlist-driven) -------
__global__ __launch_bounds__(256) void fixup_select(
    float* __restrict__ y, const float* __restrict__ g1, const float* __restrict__ b1,
    int* __restrict__ Iw, float* __restrict__ Vw,
    const int* __restrict__ rowlist, const int* __restrict__ cntr)
{
    __shared__ float ldsv[4][64];
    __shared__ int   ldsi[4][64];
    const int nflag = *cntr;
    const int w = threadIdx.x >> 6;
    const int lane = threadIdx.x & 63;
    for (int i = blockIdx.x * 4 + w; i < nflag; i += gridDim.x * 4) {
        const int r = rowlist[i];
        float* row = y + (size_t)r * B_E;
        float h[32];
#pragma unroll
        for (int q = 0; q < 8; ++q) {
            float4 v = *(const float4*)&row[q * 256 + lane * 4];
            h[q*4+0] = v.x; h[q*4+1] = v.y; h[q*4+2] = v.z; h[q*4+3] = v.w;
        }
        ln_topk_row(h, lane, g1, b1, row, Iw + r * TOPK, Vw + r * TOPK,
                    ldsv[w], ldsi[w]);
    }
}

// -------- decode (packed bf16 weights): gather 50 rows of Wp, both outputs --------
__global__ __launch_bounds__(128) void decode_packed(
    const int* __restrict__ Iw, const float* __restrict__ Vw,
    const uint* __restrict__ Wp, const float* __restrict__ bd,
    const float* __restrict__ bbias, const float* __restrict__ g2,
    const float* __restrict__ b2, float* __restrict__ recon, float* __restrict__ sep)
{
    __shared__ int   sI[TOPK];
    __shared__ float sV[TOPK];
    __shared__ float red[2];
    const int r = blockIdx.x, t = threadIdx.x;
    if (t < TOPK) { sI[t] = Iw[r * TOPK + t]; sV[t] = Vw[r * TOPK + t]; }
    __syncthreads();
    float ad[3], ab[3];
#pragma unroll
    for (int j = 0; j < 3; ++j) { ad[j] = bd[t + 128*j]; ab[j] = bbias[t + 128*j]; }
#pragma unroll 2
    for (int i = 0; i < TOPK; ++i) {
        const int   idx = sI[i];
        const float v   = sV[i];
        const uint* wp  = Wp + (size_t)idx * B_D;
#pragma unroll
        for (int j = 0; j < 3; ++j) {
            const uint u = wp[t + 128*j];
            const float wd = __uint_as_float(u << 16);
            const float wb = __uint_as_float(u & 0xFFFF0000u);
            ad[j] = fmaf(v, wd, ad[j]);
            ab[j] = fmaf(v, wb, ab[j]);
        }
    }
#pragma unroll
    for (int j = 0; j < 3; ++j) recon[(size_t)r * B_D + t + 128*j] = ad[j];
    float s = ab[0] + ab[1] + ab[2];
    s = wave_sum_f(s);
    if ((t & 63) == 0) red[t >> 6] = s;
    __syncthreads();
    const float mu = (red[0] + red[1]) * (1.f / B_D);
    __syncthreads();
    float ss = 0.f;
#pragma unroll
    for (int j = 0; j < 3; ++j) { float d = ab[j] - mu; ss += d * d; }
    ss = wave_sum_f(ss);
    if ((t & 63) == 0) red[t >> 6] = ss;
    __syncthreads();
    const float rstd = rsqrtf((red[0] + red[1]) * (1.f / B_D) + LN_EPS);
#pragma unroll
    for (int j = 0; j < 3; ++j) {
        int c = t + 128*j;
        sep[(size_t)r * B_D + c] = fmaf((ab[j] - mu) * rstd, g2[c], b2[c]);
    }
}

// -------- decode (f32 weights) — fallback only --------
__global__ __launch_bounds__(128) void decode_f32(
    const int* __restrict__ Iw, const float* __restrict__ Vw,
    const float* __restrict__ Wd, const float* __restrict__ bd,
    const float* __restrict__ Wb, const float* __restrict__ bbias,
    const float* __restrict__ g2, const float* __restrict__ b2,
    float* __restrict__ recon, float* __restrict__ sep)
{
    __shared__ int   sI[TOPK];
    __shared__ float sV[TOPK];
    __shared__ float red[2];
    const int r = blockIdx.x, t = threadIdx.x;
    if (t < TOPK) { sI[t] = Iw[r * TOPK + t]; sV[t] = Vw[r * TOPK + t]; }
    __syncthreads();
    float ad[3], ab[3];
#pragma unroll
    for (int j = 0; j < 3; ++j) { ad[j] = bd[t + 128*j]; ab[j] = bbias[t + 128*j]; }
#pragma unroll 2
    for (int i = 0; i < TOPK; ++i) {
        const int   idx = sI[i];
        const float v   = sV[i];
        const float* wd = Wd + (size_t)idx * B_D;
        const float* wb = Wb + (size_t)idx * B_D;
#pragma unroll
        for (int j = 0; j < 3; ++j) {
            ad[j] = fmaf(v, wd[t + 128*j], ad[j]);
            ab[j] = fmaf(v, wb[t + 128*j], ab[j]);
        }
    }
#pragma unroll
    for (int j = 0; j < 3; ++j) recon[(size_t)r * B_D + t + 128*j] = ad[j];
    float s = ab[0] + ab[1] + ab[2];
    s = wave_sum_f(s);
    if ((t & 63) == 0) red[t >> 6] = s;
    __syncthreads();
    const float mu = (red[0] + red[1]) * (1.f / B_D);
    __syncthreads();
    float ss = 0.f;
#pragma unroll
    for (int j = 0; j < 3; ++j) { float d = ab[j] - mu; ss += d * d; }
    ss = wave_sum_f(ss);
    if ((t & 63) == 0) red[t >> 6] = ss;
    __syncthreads();
    const float rstd = rsqrtf((red[0] + red[1]) * (1.f / B_D) + LN_EPS);
#pragma unroll
    for (int j = 0; j < 3; ++j) {
        int c = t + 128*j;
        sep[(size_t)r * B_D + c] = fmaf((ab[j] - mu) * rstd, g2[c], b2[c]);
    }
}

// ------- fallback topk (no fixup machinery) -------
__global__ __launch_bounds__(256) void topk_only(
    float* __restrict__ y, const float* __restrict__ g1, const float* __restrict__ b1,
    int* __restrict__ Iw, float* __restrict__ Vw)
{
    __shared__ float ldsv[4][64];
    __shared__ int   ldsi[4][64];
    const int lane = threadIdx.x & 63;
    const int w = threadIdx.x >> 6;
    const int r = blockIdx.x * 4 + w;
    float* row = y + (size_t)r * B_E;
    float h[32];
#pragma unroll
    for (int q = 0; q < 8; ++q) {
        float4 v = *(const float4*)&row[q * 256 + lane * 4];
        h[q*4+0] = v.x; h[q*4+1] = v.y; h[q*4+2] = v.z; h[q*4+3] = v.w;
    }
    ln_topk_row(h, lane, g1, b1, row, Iw + r * TOPK, Vw + r * TOPK, ldsv[w], ldsi[w]);
}

extern "C" void kernel_launch(void* const* d_in, const int* in_sizes, int n_in,
                              void* d_out, int out_size, void* d_ws, size_t ws_size,
                              hipStream_t stream)
{
    const float* x  = (const float*)d_in[0];
    const float* We = (const float*)d_in[1];
    const float* be = (const float*)d_in[2];
    const float* g1 = (const float*)d_in[3];
    const float* b1 = (const float*)d_in[4];
    const float* Wd = (const float*)d_in[5];
    const float* bd = (const float*)d_in[6];
    const float* Wb = (const float*)d_in[7];
    const float* bb = (const float*)d_in[8];
    const float* g2 = (const float*)d_in[9];
    const float* b2 = (const float*)d_in[10];

    const int Brows = in_sizes[0] / B_D;               // 16384
    float* recon  = (float*)d_out;
    float* sparse = recon + (size_t)Brows * B_D;       // [B,2048]
    float* sep    = sparse + (size_t)Brows * B_E;

    char* ws = (char*)d_ws;
    int*   Iw      = (int*)ws;                         // 3,276,800
    float* Vw      = (float*)(ws + 3276800);           // 3,276,800
    int*   rowlist = (int*)(ws + 6619136);             // 65,536
    int*   cntr    = (int*)(ws + 6684672);             // 64 (padded)
    const size_t apOff = 6688768;                      // Ap: 25,165,824 (aliased by Wp after enc)
    const size_t bpOff = apOff + (size_t)64 * NKP * 2048 * 16;
    const size_t need  = bpOff + (size_t)8 * NKP * 2048 * 16;    // ~35.0 MB

    if (ws_size >= need) {
        ushort* Ap = (ushort*)(ws + apOff);
        ushort* Bp = (ushort*)(ws + bpOff);
        uint*   Wp = (uint*)(ws + apOff);              // aliases Ap (enc done before pack_W blocks)
        pack_AB<<<dim3(NKP, 72), dim3(256), 0, stream>>>(x, We, Ap, Bp, cntr);
        enc_mfma256_p<<<dim3(512), dim3(512), 0, stream>>>(Ap, Bp, be, sparse);
        topk_packW<<<dim3(Brows / 4 + 1024), dim3(256), 0, stream>>>(
            sparse, g1, b1, Iw, Vw, rowlist, cntr, Wd, Wb, Wp, Brows / 4);
        fixup_recompute<<<dim3(8, Brows / 8), dim3(256), 0, stream>>>(x, We, be, sparse, rowlist, cntr);
        fixup_select<<<dim3(256), dim3(256), 0, stream>>>(sparse, g1, b1, Iw, Vw, rowlist, cntr);
        decode_packed<<<dim3(Brows), dim3(128), 0, stream>>>(Iw, Vw, Wp, bd, bb, g2, b2, recon, sep);
    } else {
        enc_gemm_f32<<<dim3(16, 128), dim3(256), 0, stream>>>(x, We, be, sparse);
        topk_only<<<dim3(Brows / 4), dim3(256), 0, stream>>>(sparse, g1, b1, Iw, Vw);
        decode_f32<<<dim3(Brows), dim3(128), 0, stream>>>(Iw, Vw, Wd, bd, Wb, bb, g2, b2, recon, sep);
    }
}

// Round 13
// 267.275 us; speedup vs baseline: 1.0869x; 1.0869x over previous
//
#include <hip/hip_runtime.h>
#include <hip/hip_bf16.h>
#include <stdint.h>

#define B_D   384
#define B_E   2048
#define TOPK  50
#define LN_EPS 1e-5f
#define NKP   12            // physical packed K-steps of 64 (6 hi + 6 lo)
#define FIX_WINDOW 2e-4f

typedef short bf16x8 __attribute__((ext_vector_type(8)));
typedef float f32x4  __attribute__((ext_vector_type(4)));

// ---------------- wave helpers (wave64) ----------------
__device__ __forceinline__ float wave_sum_f(float v) {
#pragma unroll
    for (int d = 1; d < 64; d <<= 1) v += __shfl_xor(v, d, 64);
    return v;
}
__device__ __forceinline__ int wave_sum_i(int v) {
#pragma unroll
    for (int d = 1; d < 64; d <<= 1) v += __shfl_xor(v, d, 64);
    return v;
}
__device__ __forceinline__ float wave_max_f(float v) {
#pragma unroll
    for (int d = 1; d < 64; d <<= 1) v = fmaxf(v, __shfl_xor(v, d, 64));
    return v;
}

__device__ __forceinline__ ushort f2bf_hi(float v) {
    __hip_bfloat16 b = __float2bfloat16(v);
    return *(ushort*)&b;
}
__device__ __forceinline__ ushort f2bf_lo(float v) {
    __hip_bfloat16 b = __float2bfloat16(v);
    float rem = v - __bfloat162float(b);
    __hip_bfloat16 l = __float2bfloat16(rem);
    return *(ushort*)&l;
}

__device__ __forceinline__ void llds16(const void* g, void* l) {
    __builtin_amdgcn_global_load_lds((const __attribute__((address_space(1))) void*)g,
                                     (__attribute__((address_space(3))) void*)l, 16, 0, 0);
}

// ---------------- fused pack: A (mt=0..63) and B (y=64..71) tiles ----------------
__global__ __launch_bounds__(256) void pack_AB(
    const float* __restrict__ x, const float* __restrict__ We,
    ushort* __restrict__ Ap, ushort* __restrict__ Bp, int* __restrict__ cntr)
{
    const int ks = blockIdx.x, yb = blockIdx.y, t = threadIdx.x;
    if (cntr && t == 0 && ks == 0 && yb == 0) *cntr = 0;
    if (yb < 64) {
        const int mt = yb;
#pragma unroll
        for (int q = 0; q < 8; ++q) {
            const int s = q * 256 + t;          // 0..2047
            const int m = s & 255, kg = s >> 8;
            const int kp = ks * 64 + kg * 8;    // 0..767
            const int hi = (kp < 384);
            const int ksrc = hi ? kp : kp - 384;
            const float* src = x + (size_t)(mt * 256 + m) * B_D + ksrc;
            float4 v0 = *(const float4*)src;
            float4 v1 = *(const float4*)(src + 4);
            float vv[8] = {v0.x, v0.y, v0.z, v0.w, v1.x, v1.y, v1.z, v1.w};
            ushort o[8];
#pragma unroll
            for (int e = 0; e < 8; ++e)
                o[e] = hi ? f2bf_hi(vv[e]) : f2bf_lo(vv[e]);
            *(uint4*)(Ap + ((size_t)(mt * NKP + ks) * 2048 + s) * 8) = *(uint4*)o;
        }
    } else {
        const int nt = yb - 64;
#pragma unroll
        for (int q = 0; q < 8; ++q) {
            const int s = q * 256 + t;
            const int nl = s & 255, kg = s >> 8;
            const int kp = ks * 64 + kg * 8;
            const int hi = (kp < 384);
            const int ksrc = hi ? kp : kp - 384;
            const int ng = nt * 256 + nl;
            ushort o[8];
#pragma unroll
            for (int e = 0; e < 8; ++e) {
                float v = We[(size_t)(ksrc + e) * B_E + ng];
                o[e] = hi ? f2bf_hi(v) : f2bf_lo(v);
            }
            *(uint4*)(Bp + ((size_t)(nt * NKP + ks) * 2048 + s) * 8) = *(uint4*)o;
        }
    }
}

// ------- MFMA encoder GEMM, 256x256 tile, 2-phase dbuf, 3-products-per-stage -------
// Per half-tile hk (0..11, K=32 of the base k range): stage {Ah,Al,Bh,Bl}(hk) once,
// compute acc += Ah*Bh + Ah*Bl + Al*Bh (96 MFMA / barrier-pair). Same sync template
// as the verified 2-phase kernel: STAGE(hk+1) -> compute(hk) -> __syncthreads().
__global__ __launch_bounds__(512, 2) void enc_mfma256b(
    const ushort* __restrict__ Ap, const ushort* __restrict__ Bp,
    const float* __restrict__ be, float* __restrict__ y)
{
    __shared__ __align__(16) ushort Ah[2][8192];   // 2 x 16 KB
    __shared__ __align__(16) ushort Al[2][8192];
    __shared__ __align__(16) ushort Bh[2][8192];
    __shared__ __align__(16) ushort Bl[2][8192];
    const int t = threadIdx.x, lane = t & 63, w = t >> 6;
    const int wr = w >> 2, wc = w & 3;
    const int gid = blockIdx.x;
    const int swz = (gid & 7) * 64 + (gid >> 3);   // XCD-aware (512 % 8 == 0, bijective)
    const int nt = swz & 7, mt = swz >> 3;
    const ushort* gA = Ap + (size_t)mt * NKP * 16384;
    const ushort* gB = Bp + (size_t)nt * NKP * 16384;

    f32x4 acc[8][4];
#pragma unroll
    for (int i = 0; i < 8; ++i)
#pragma unroll
        for (int j = 0; j < 4; ++j)
#pragma unroll
            for (int r = 0; r < 4; ++r) acc[i][j][r] = 0.f;

    const int l15 = lane & 15, l4 = lane >> 4;

#define STAGEH(hk_, b_)                                                         \
    {                                                                           \
        const int hh = (hk_);                                                   \
        const int kt = hh >> 1, hf = hh & 1;                                    \
        const ushort* ah_ = gA + (size_t)kt * 16384 + hf * 8192 + t * 8;        \
        const ushort* al_ = gA + (size_t)(kt + 6) * 16384 + hf * 8192 + t * 8;  \
        const ushort* bh_ = gB + (size_t)kt * 16384 + hf * 8192 + t * 8;        \
        const ushort* bl_ = gB + (size_t)(kt + 6) * 16384 + hf * 8192 + t * 8;  \
        llds16(ah_,        &Ah[b_][t * 8]);                                     \
        llds16(ah_ + 4096, &Ah[b_][4096 + t * 8]);                              \
        llds16(al_,        &Al[b_][t * 8]);                                     \
        llds16(al_ + 4096, &Al[b_][4096 + t * 8]);                              \
        llds16(bh_,        &Bh[b_][t * 8]);                                     \
        llds16(bh_ + 4096, &Bh[b_][4096 + t * 8]);                              \
        llds16(bl_,        &Bl[b_][t * 8]);                                     \
        llds16(bl_ + 4096, &Bl[b_][4096 + t * 8]);                              \
    }

    STAGEH(0, 0);
    __syncthreads();                       // drains prologue stage

    for (int hk = 0; hk < 12; ++hk) {
        const int sl = hk & 1;
        if (hk + 1 < 12) STAGEH(hk + 1, sl ^ 1);
        bf16x8 bhf[4], ahf[8];
#pragma unroll
        for (int j = 0; j < 4; ++j)
            bhf[j] = *(const bf16x8*)&Bh[sl][(l4 * 256 + wc * 64 + j * 16 + l15) * 8];
#pragma unroll
        for (int i = 0; i < 8; ++i)
            ahf[i] = *(const bf16x8*)&Ah[sl][(l4 * 256 + wr * 128 + i * 16 + l15) * 8];
#pragma unroll
        for (int i = 0; i < 8; ++i)
#pragma unroll
            for (int j = 0; j < 4; ++j)
                acc[i][j] = __builtin_amdgcn_mfma_f32_16x16x32_bf16(ahf[i], bhf[j], acc[i][j], 0, 0, 0);
        bf16x8 blf[4];
#pragma unroll
        for (int j = 0; j < 4; ++j)
            blf[j] = *(const bf16x8*)&Bl[sl][(l4 * 256 + wc * 64 + j * 16 + l15) * 8];
#pragma unroll
        for (int i = 0; i < 8; ++i)
#pragma unroll
            for (int j = 0; j < 4; ++j)
                acc[i][j] = __builtin_amdgcn_mfma_f32_16x16x32_bf16(ahf[i], blf[j], acc[i][j], 0, 0, 0);
        bf16x8 alf[8];
#pragma unroll
        for (int i = 0; i < 8; ++i)
            alf[i] = *(const bf16x8*)&Al[sl][(l4 * 256 + wr * 128 + i * 16 + l15) * 8];
#pragma unroll
        for (int i = 0; i < 8; ++i)
#pragma unroll
            for (int j = 0; j < 4; ++j)
                acc[i][j] = __builtin_amdgcn_mfma_f32_16x16x32_bf16(alf[i], bhf[j], acc[i][j], 0, 0, 0);
        if (hk + 1 < 12) __syncthreads();  // frees slot sl for STAGE(hk+2)
    }
#undef STAGEH

    float bev[4];
#pragma unroll
    for (int j = 0; j < 4; ++j) bev[j] = be[nt * 256 + wc * 64 + j * 16 + l15];
#pragma unroll
    for (int i = 0; i < 8; ++i)
#pragma unroll
        for (int j = 0; j < 4; ++j)
#pragma unroll
            for (int r = 0; r < 4; ++r) {
                const int row = mt * 256 + wr * 128 + i * 16 + l4 * 4 + r;
                const int col = nt * 256 + wc * 64 + j * 16 + l15;
                y[(size_t)row * B_E + col] = acc[i][j][r] + bev[j];
            }
}

// ---------------- fp32 fallback GEMM ----------------
__global__ __launch_bounds__(256) void enc_gemm_f32(
    const float* __restrict__ x, const float* __restrict__ We,
    const float* __restrict__ be, float* __restrict__ y)
{
    __shared__ float As[8][128];
    __shared__ float Bs[8][128];
    const int t  = threadIdx.x;
    const int m0 = blockIdx.y * 128;
    const int n0 = blockIdx.x * 128;
    const int tx = t & 15, ty = t >> 4;
    const int la_m = t >> 1, la_k = (t & 1) * 4;
    const int lb_k = t >> 5, lb_c = (t & 31) * 4;

    float acc[8][8];
#pragma unroll
    for (int i = 0; i < 8; ++i)
#pragma unroll
        for (int j = 0; j < 8; ++j) acc[i][j] = 0.f;

    for (int k0 = 0; k0 < B_D; k0 += 8) {
        float4 a = *(const float4*)&x[(size_t)(m0 + la_m) * B_D + k0 + la_k];
        float4 b = *(const float4*)&We[(size_t)(k0 + lb_k) * B_E + n0 + lb_c];
        __syncthreads();
        As[la_k + 0][la_m] = a.x;
        As[la_k + 1][la_m] = a.y;
        As[la_k + 2][la_m] = a.z;
        As[la_k + 3][la_m] = a.w;
        *(float4*)&Bs[lb_k][lb_c] = b;
        __syncthreads();
#pragma unroll
        for (int kk = 0; kk < 8; ++kk) {
            float4 a0 = *(const float4*)&As[kk][ty * 4];
            float4 a1 = *(const float4*)&As[kk][ty * 4 + 64];
            float4 b0 = *(const float4*)&Bs[kk][tx * 4];
            float4 b1 = *(const float4*)&Bs[kk][tx * 4 + 64];
            float av[8] = {a0.x,a0.y,a0.z,a0.w,a1.x,a1.y,a1.z,a1.w};
            float bv[8] = {b0.x,b0.y,b0.z,b0.w,b1.x,b1.y,b1.z,b1.w};
#pragma unroll
            for (int i = 0; i < 8; ++i)
#pragma unroll
                for (int j = 0; j < 8; ++j)
                    acc[i][j] = fmaf(av[i], bv[j], acc[i][j]);
        }
    }
    float4 beL = *(const float4*)&be[n0 + tx * 4];
    float4 beH = *(const float4*)&be[n0 + 64 + tx * 4];
    float bl[8] = {beL.x,beL.y,beL.z,beL.w,beH.x,beH.y,beH.z,beH.w};
#pragma unroll
    for (int i = 0; i < 8; ++i) {
        int row = m0 + ty * 4 + (i & 3) + (i >> 2) * 64;
        float4 o0 = {acc[i][0]+bl[0], acc[i][1]+bl[1], acc[i][2]+bl[2], acc[i][3]+bl[3]};
        float4 o1 = {acc[i][4]+bl[4], acc[i][5]+bl[5], acc[i][6]+bl[6], acc[i][7]+bl[7]};
        *(float4*)&y[(size_t)row * B_E + n0 + tx * 4]      = o0;
        *(float4*)&y[(size_t)row * B_E + n0 + 64 + tx * 4] = o1;
    }
}

// ------- shared per-row LN -> relu -> exact top-50; returns ambiguity flag -------
__device__ __forceinline__ int ln_topk_row(
    float (&h)[32], int lane, const float* __restrict__ g1, const float* __restrict__ b1,
    float* __restrict__ row, int* __restrict__ IwR, float* __restrict__ VwR,
    float* __restrict__ ldsv, int* __restrict__ ldsi)
{
    float s = 0.f;
#pragma unroll
    for (int j = 0; j < 32; ++j) s += h[j];
    s = wave_sum_f(s);
    const float mu = s * (1.f / B_E);
    float ss = 0.f;
#pragma unroll
    for (int j = 0; j < 32; ++j) { float d = h[j] - mu; ss += d * d; }
    ss = wave_sum_f(ss);
    const float rstd = rsqrtf(ss * (1.f / B_E) + LN_EPS);
#pragma unroll
    for (int q = 0; q < 8; ++q) {
        float4 g  = *(const float4*)&g1[q * 256 + lane * 4];
        float4 bb = *(const float4*)&b1[q * 256 + lane * 4];
        float gg[4]  = {g.x,g.y,g.z,g.w};
        float bbv[4] = {bb.x,bb.y,bb.z,bb.w};
#pragma unroll
        for (int i = 0; i < 4; ++i) {
            int j = q*4+i;
            h[j] = fmaxf(fmaf((h[j] - mu) * rstd, gg[i], bbv[i]), 0.f);
        }
    }
    float mx = h[0];
#pragma unroll
    for (int j = 1; j < 32; ++j) mx = fmaxf(mx, h[j]);
    mx = wave_max_f(mx);

    // Phase 1: value-space bisection; invariant count(>=vlo) = cl >= TOPK.
    float vlo = 0.f, vhi = __uint_as_float(__float_as_uint(mx) + 1u);
    int cl = 2048;
    bool window = false;
    for (int it = 0; it < 20; ++it) {
        float mid = 0.5f * (vlo + vhi);
        if (it == 0 && 2.2f > vlo && 2.2f < vhi) mid = 2.2f;
        if (!(mid > vlo && mid < vhi)) break;
        int c = 0;
#pragma unroll
        for (int j = 0; j < 32; ++j)
            c += (int)__popcll(__ballot(h[j] >= mid));
        if (c >= TOPK) { vlo = mid; cl = c; if (c <= 64) { window = true; break; } }
        else vhi = mid;
    }
    unsigned lo = __float_as_uint(vlo);
    if (!window) {
        unsigned hi = __float_as_uint(vhi);
        while (hi - lo > 1u) {
            const unsigned mid = lo + ((hi - lo) >> 1);
            const float mf = __uint_as_float(mid);
            int c = 0;
#pragma unroll
            for (int j = 0; j < 32; ++j)
                c += (int)__popcll(__ballot(h[j] >= mf));
            if (c >= TOPK) { lo = mid; cl = c; if (c <= 64) break; }
            else hi = mid;
        }
    }
    const float T0 = __uint_as_float(lo);

    unsigned selmask = 0u;
    int flag = 0;
    bool fastSel = (cl <= 64 && T0 > 0.f);

    if (fastSel) {
        ldsv[lane] = -1.f;
        ldsi[lane] = 1 << 20;
        asm volatile("s_waitcnt lgkmcnt(0)" ::: "memory");
        int base = 0;
#pragma unroll
        for (int j = 0; j < 32; ++j) {
            const bool p = (h[j] >= T0);
            const unsigned long long m = __ballot(p);
            if (p) {
                const int pos = base + (int)__popcll(m & ((1ull << lane) - 1ull));
                ldsv[pos] = h[j];
                ldsi[pos] = (j >> 2) * 256 + lane * 4 + (j & 3);
            }
            base += (int)__popcll(m);
        }
        asm volatile("s_waitcnt lgkmcnt(0)" ::: "memory");
        float sv = ldsv[lane];
        int   si = ldsi[lane];
#pragma unroll
        for (int k = 2; k <= 64; k <<= 1) {
#pragma unroll
            for (int jj = k >> 1; jj > 0; jj >>= 1) {
                const float ov = __shfl_xor(sv, jj, 64);
                const int   oi = __shfl_xor(si, jj, 64);
                const bool dirUp = ((lane & k) == 0);
                const bool lower = ((lane & jj) == 0);
                const bool mineBefore = (sv > ov) || (sv == ov && si < oi);
                const bool keep = (lower == dirUp) ? mineBefore : !mineBefore;
                if (!keep) { sv = ov; si = oi; }
            }
        }
        const float T    = __shfl(sv, TOPK - 1, 64);
        const int   idxT = __shfl(si, TOPK - 1, 64);
        float v51;
        if (cl > TOPK) {
            v51 = __shfl(sv, TOPK, 64);
        } else {
            float bb = -1.f;
#pragma unroll
            for (int j = 0; j < 32; ++j) bb = (h[j] < T0) ? fmaxf(bb, h[j]) : bb;
            v51 = wave_max_f(bb);
        }
        flag = (T - v51 < FIX_WINDOW) ? 1 : 0;
#pragma unroll
        for (int j = 0; j < 32; ++j) {
            const int e = (j >> 2) * 256 + lane * 4 + (j & 3);
            if (h[j] > T || (h[j] == T && e <= idxT)) selmask |= (1u << j);
        }
        if (lane < TOPK) { IwR[lane] = si; VwR[lane] = sv; }
    } else {
        const float T = T0;
        int cgt = 0, ceq = 0;
        float below = -1.f;
#pragma unroll
        for (int j = 0; j < 32; ++j) {
            cgt += (h[j] > T); ceq += (h[j] == T);
            if (h[j] < T) below = fmaxf(below, h[j]);
        }
        const int cgt_t = wave_sum_i(cgt);
        const int ceq_t = wave_sum_i(ceq);
        below = wave_max_f(below);
        const int need = TOPK - cgt_t;

        if (cgt_t + ceq_t == TOPK) {
#pragma unroll
            for (int j = 0; j < 32; ++j) if (h[j] >= T) selmask |= (1u << j);
        } else {
            int base = 0;
            for (int q = 0; q < 8; ++q) {
                int tc = 0;
#pragma unroll
                for (int i = 0; i < 4; ++i) tc += (h[q*4+i] == T);
                int ip = tc;
#pragma unroll
                for (int d = 1; d < 64; d <<= 1) {
                    int o = __shfl_up(ip, d, 64);
                    if (lane >= d) ip += o;
                }
                int rk  = base + ip - tc;
                int tot = __shfl(ip, 63, 64);
#pragma unroll
                for (int i = 0; i < 4; ++i) {
                    int j = q*4+i;
                    if (h[j] > T) selmask |= (1u << j);
                    else if (h[j] == T) { if (rk < need) selmask |= (1u << j); rk++; }
                }
                base += tot;
            }
        }
        if (T > 0.f) {
            if (cgt_t + ceq_t != TOPK && ceq_t > need) flag = 1;
            else if (T - below < FIX_WINDOW) flag = 1;
        }
        const int myc = __popc(selmask);
        int ip = myc;
#pragma unroll
        for (int d = 1; d < 64; d <<= 1) {
            int o = __shfl_up(ip, d, 64);
            if (lane >= d) ip += o;
        }
        int pos = ip - myc;
        for (int j = 0; j < 32; ++j) {
            if ((selmask >> j) & 1u) {
                int e = (j >> 2) * 256 + lane * 4 + (j & 3);
                IwR[pos] = e;
                VwR[pos] = h[j];
                pos++;
            }
        }
    }

#pragma unroll
    for (int q = 0; q < 8; ++q) {
        float4 o;
        o.x = ((selmask >> (q*4+0)) & 1u) ? h[q*4+0] : 0.f;
        o.y = ((selmask >> (q*4+1)) & 1u) ? h[q*4+1] : 0.f;
        o.z = ((selmask >> (q*4+2)) & 1u) ? h[q*4+2] : 0.f;
        o.w = ((selmask >> (q*4+3)) & 1u) ? h[q*4+3] : 0.f;
        *(float4*)&row[q * 256 + lane * 4] = o;
    }
    return flag;
}

// ------- topk (blocks 0..nTopk-1) fused with pack_W (blocks nTopk..nTopk+1023) -------
__global__ __launch_bounds__(256) void topk_packW(
    float* __restrict__ y, const float* __restrict__ g1, const float* __restrict__ b1,
    int* __restrict__ Iw, float* __restrict__ Vw,
    int* __restrict__ rowlist, int* __restrict__ cntr,
    const float* __restrict__ Wd, const float* __restrict__ Wb, uint* __restrict__ Wp,
    int nTopk)
{
    __shared__ float ldsv[4][64];
    __shared__ int   ldsi[4][64];
    const int bid = blockIdx.x;
    const int t = threadIdx.x;
    if (bid >= nTopk) {
        const int e = (bid - nTopk) * 2 + (t >> 7);
        const int tt = t & 127;
#pragma unroll
        for (int j = 0; j < 3; ++j) {
            const int c = tt + 128 * j;
            const ushort d = f2bf_hi(Wd[(size_t)e * B_D + c]);
            const ushort b = f2bf_hi(Wb[(size_t)e * B_D + c]);
            Wp[(size_t)e * B_D + c] = ((uint)b << 16) | (uint)d;
        }
        return;
    }
    const int lane = t & 63;
    const int w = t >> 6;
    const int r = bid * 4 + w;
    float* row = y + (size_t)r * B_E;
    float h[32];
#pragma unroll
    for (int q = 0; q < 8; ++q) {
        float4 v = *(const float4*)&row[q * 256 + lane * 4];
        h[q*4+0] = v.x; h[q*4+1] = v.y; h[q*4+2] = v.z; h[q*4+3] = v.w;
    }
    int flag = ln_topk_row(h, lane, g1, b1, row, Iw + r * TOPK, Vw + r * TOPK,
                           ldsv[w], ldsi[w]);
    if (rowlist && lane == 0 && flag) {
        int p = atomicAdd(cntr, 1);
        rowlist[p] = r;
    }
}

// ------- fixup phase 1: exact fp32 recompute of flagged rows (pre-LN y) -------
__global__ __launch_bounds__(256) void fixup_recompute(
    const float* __restrict__ x, const float* __restrict__ We, const float* __restrict__ be,
    float* __restrict__ y, const int* __restrict__ rowlist, const int* __restrict__ cntr)
{
    const int nflag = *cntr;
    const int rb = blockIdx.y * 8;
    if (rb >= nflag) return;
    const int nact = min(nflag - rb, 8);
    const int t = threadIdx.x;

    __shared__ float xs[8][B_D];
    __shared__ int   rIdx[8];
    if (t < 8) rIdx[t] = (t < nact) ? rowlist[rb + t] : -1;
    __syncthreads();
#pragma unroll
    for (int i = 0; i < 8; ++i) {
        if (i < nact) {
            const float* src = x + (size_t)rIdx[i] * B_D;
            for (int j = t; j < B_D; j += 256) xs[i][j] = src[j];
        } else {
            for (int j = t; j < B_D; j += 256) xs[i][j] = 0.f;
        }
    }
    __syncthreads();

    const int c = blockIdx.x * 256 + t;
    const float bc = be[c];
    float acc[8];
#pragma unroll
    for (int i = 0; i < 8; ++i) acc[i] = bc;
#pragma unroll 4
    for (int k = 0; k < B_D; ++k) {
        const float w = We[(size_t)k * B_E + c];
#pragma unroll
        for (int i = 0; i < 8; ++i) acc[i] = fmaf(xs[i][k], w, acc[i]);
    }
#pragma unroll
    for (int i = 0; i < 8; ++i)
        if (i < nact) y[(size_t)rIdx[i] * B_E + c] = acc[i];
}

// ------- fixup phase 2: redo LN+topk on flagged rows (rowlist-driven) -------
__global__ __launch_bounds__(256) void fixup_select(
    float* __restrict__ y, const float* __restrict__ g1, const float* __restrict__ b1,
    int* __restrict__ Iw, float* __restrict__ Vw,
    const int* __restrict__ rowlist, const int* __restrict__ cntr)
{
    __shared__ float ldsv[4][64];
    __shared__ int   ldsi[4][64];
    const int nflag = *cntr;
    const int w = threadIdx.x >> 6;
    const int lane = threadIdx.x & 63;
    for (int i = blockIdx.x * 4 + w; i < nflag; i += gridDim.x * 4) {
        const int r = rowlist[i];
        float* row = y + (size_t)r * B_E;
        float h[32];
#pragma unroll
        for (int q = 0; q < 8; ++q) {
            float4 v = *(const float4*)&row[q * 256 + lane * 4];
            h[q*4+0] = v.x; h[q*4+1] = v.y; h[q*4+2] = v.z; h[q*4+3] = v.w;
        }
        ln_topk_row(h, lane, g1, b1, row, Iw + r * TOPK, Vw + r * TOPK,
                    ldsv[w], ldsi[w]);
    }
}

// -------- decode (packed bf16 weights): gather 50 rows of Wp, both outputs --------
__global__ __launch_bounds__(128) void decode_packed(
    const int* __restrict__ Iw, const float* __restrict__ Vw,
    const uint* __restrict__ Wp, const float* __restrict__ bd,
    const float* __restrict__ bbias, const float* __restrict__ g2,
    const float* __restrict__ b2, float* __restrict__ recon, float* __restrict__ sep)
{
    __shared__ int   sI[TOPK];
    __shared__ float sV[TOPK];
    __shared__ float red[2];
    const int r = blockIdx.x, t = threadIdx.x;
    if (t < TOPK) { sI[t] = Iw[r * TOPK + t]; sV[t] = Vw[r * TOPK + t]; }
    __syncthreads();
    float ad[3], ab[3];
#pragma unroll
    for (int j = 0; j < 3; ++j) { ad[j] = bd[t + 128*j]; ab[j] = bbias[t + 128*j]; }
#pragma unroll 2
    for (int i = 0; i < TOPK; ++i) {
        const int   idx = sI[i];
        const float v   = sV[i];
        const uint* wp  = Wp + (size_t)idx * B_D;
#pragma unroll
        for (int j = 0; j < 3; ++j) {
            const uint u = wp[t + 128*j];
            const float wd = __uint_as_float(u << 16);
            const float wb = __uint_as_float(u & 0xFFFF0000u);
            ad[j] = fmaf(v, wd, ad[j]);
            ab[j] = fmaf(v, wb, ab[j]);
        }
    }
#pragma unroll
    for (int j = 0; j < 3; ++j) recon[(size_t)r * B_D + t + 128*j] = ad[j];
    float s = ab[0] + ab[1] + ab[2];
    s = wave_sum_f(s);
    if ((t & 63) == 0) red[t >> 6] = s;
    __syncthreads();
    const float mu = (red[0] + red[1]) * (1.f / B_D);
    __syncthreads();
    float ss = 0.f;
#pragma unroll
    for (int j = 0; j < 3; ++j) { float d = ab[j] - mu; ss += d * d; }
    ss = wave_sum_f(ss);
    if ((t & 63) == 0) red[t >> 6] = ss;
    __syncthreads();
    const float rstd = rsqrtf((red[0] + red[1]) * (1.f / B_D) + LN_EPS);
#pragma unroll
    for (int j = 0; j < 3; ++j) {
        int c = t + 128*j;
        sep[(size_t)r * B_D + c] = fmaf((ab[j] - mu) * rstd, g2[c], b2[c]);
    }
}

// -------- decode (f32 weights) — fallback only --------
__global__ __launch_bounds__(128) void decode_f32(
    const int* __restrict__ Iw, const float* __restrict__ Vw,
    const float* __restrict__ Wd, const float* __restrict__ bd,
    const float* __restrict__ Wb, const float* __restrict__ bbias,
    const float* __restrict__ g2, const float* __restrict__ b2,
    float* __restrict__ recon, float* __restrict__ sep)
{
    __shared__ int   sI[TOPK];
    __shared__ float sV[TOPK];
    __shared__ float red[2];
    const int r = blockIdx.x, t = threadIdx.x;
    if (t < TOPK) { sI[t] = Iw[r * TOPK + t]; sV[t] = Vw[r * TOPK + t]; }
    __syncthreads();
    float ad[3], ab[3];
#pragma unroll
    for (int j = 0; j < 3; ++j) { ad[j] = bd[t + 128*j]; ab[j] = bbias[t + 128*j]; }
#pragma unroll 2
    for (int i = 0; i < TOPK; ++i) {
        const int   idx = sI[i];
        const float v   = sV[i];
        const float* wd = Wd + (size_t)idx * B_D;
        const float* wb = Wb + (size_t)idx * B_D;
#pragma unroll
        for (int j = 0; j < 3; ++j) {
            ad[j] = fmaf(v, wd[t + 128*j], ad[j]);
            ab[j] = fmaf(v, wb[t + 128*j], ab[j]);
        }
    }
#pragma unroll
    for (int j = 0; j < 3; ++j) recon[(size_t)r * B_D + t + 128*j] = ad[j];
    float s = ab[0] + ab[1] + ab[2];
    s = wave_sum_f(s);
    if ((t & 63) == 0) red[t >> 6] = s;
    __syncthreads();
    const float mu = (red[0] + red[1]) * (1.f / B_D);
    __syncthreads();
    float ss = 0.f;
#pragma unroll
    for (int j = 0; j < 3; ++j) { float d = ab[j] - mu; ss += d * d; }
    ss = wave_sum_f(ss);
    if ((t & 63) == 0) red[t >> 6] = ss;
    __syncthreads();
    const float rstd = rsqrtf((red[0] + red[1]) * (1.f / B_D) + LN_EPS);
#pragma unroll
    for (int j = 0; j < 3; ++j) {
        int c = t + 128*j;
        sep[(size_t)r * B_D + c] = fmaf((ab[j] - mu) * rstd, g2[c], b2[c]);
    }
}

// ------- fallback topk (no fixup machinery) -------
__global__ __launch_bounds__(256) void topk_only(
    float* __restrict__ y, const float* __restrict__ g1, const float* __restrict__ b1,
    int* __restrict__ Iw, float* __restrict__ Vw)
{
    __shared__ float ldsv[4][64];
    __shared__ int   ldsi[4][64];
    const int lane = threadIdx.x & 63;
    const int w = threadIdx.x >> 6;
    const int r = blockIdx.x * 4 + w;
    float* row = y + (size_t)r * B_E;
    float h[32];
#pragma unroll
    for (int q = 0; q < 8; ++q) {
        float4 v = *(const float4*)&row[q * 256 + lane * 4];
        h[q*4+0] = v.x; h[q*4+1] = v.y; h[q*4+2] = v.z; h[q*4+3] = v.w;
    }
    ln_topk_row(h, lane, g1, b1, row, Iw + r * TOPK, Vw + r * TOPK, ldsv[w], ldsi[w]);
}

extern "C" void kernel_launch(void* const* d_in, const int* in_sizes, int n_in,
                              void* d_out, int out_size, void* d_ws, size_t ws_size,
                              hipStream_t stream)
{
    const float* x  = (const float*)d_in[0];
    const float* We = (const float*)d_in[1];
    const float* be = (const float*)d_in[2];
    const float* g1 = (const float*)d_in[3];
    const float* b1 = (const float*)d_in[4];
    const float* Wd = (const float*)d_in[5];
    const float* bd = (const float*)d_in[6];
    const float* Wb = (const float*)d_in[7];
    const float* bb = (const float*)d_in[8];
    const float* g2 = (const float*)d_in[9];
    const float* b2 = (const float*)d_in[10];

    const int Brows = in_sizes[0] / B_D;               // 16384
    float* recon  = (float*)d_out;
    float* sparse = recon + (size_t)Brows * B_D;       // [B,2048]
    float* sep    = sparse + (size_t)Brows * B_E;

    char* ws = (char*)d_ws;
    int*   Iw      = (int*)ws;                         // 3,276,800
    float* Vw      = (float*)(ws + 3276800);           // 3,276,800
    int*   rowlist = (int*)(ws + 6619136);             // 65,536
    int*   cntr    = (int*)(ws + 6684672);             // 64 (padded)
    const size_t apOff = 6688768;                      // Ap: 25,165,824 (aliased by Wp after enc)
    const size_t bpOff = apOff + (size_t)64 * NKP * 2048 * 16;
    const size_t need  = bpOff + (size_t)8 * NKP * 2048 * 16;    // ~35.0 MB

    if (ws_size >= need) {
        ushort* Ap = (ushort*)(ws + apOff);
        ushort* Bp = (ushort*)(ws + bpOff);
        uint*   Wp = (uint*)(ws + apOff);              // aliases Ap (enc done before pack_W blocks)
        pack_AB<<<dim3(NKP, 72), dim3(256), 0, stream>>>(x, We, Ap, Bp, cntr);
        enc_mfma256b<<<dim3(512), dim3(512), 0, stream>>>(Ap, Bp, be, sparse);
        topk_packW<<<dim3(Brows / 4 + 1024), dim3(256), 0, stream>>>(
            sparse, g1, b1, Iw, Vw, rowlist, cntr, Wd, Wb, Wp, Brows / 4);
        fixup_recompute<<<dim3(8, Brows / 8), dim3(256), 0, stream>>>(x, We, be, sparse, rowlist, cntr);
        fixup_select<<<dim3(256), dim3(256), 0, stream>>>(sparse, g1, b1, Iw, Vw, rowlist, cntr);
        decode_packed<<<dim3(Brows), dim3(128), 0, stream>>>(Iw, Vw, Wp, bd, bb, g2, b2, recon, sep);
    } else {
        enc_gemm_f32<<<dim3(16, 128), dim3(256), 0, stream>>>(x, We, be, sparse);
        topk_only<<<dim3(Brows / 4), dim3(256), 0, stream>>>(sparse, g1, b1, Iw, Vw);
        decode_f32<<<dim3(Brows), dim3(128), 0, stream>>>(Iw, Vw, Wd, bd, Wb, bb, g2, b2, recon, sep);
    }
}

// Round 14
// 266.800 us; speedup vs baseline: 1.0888x; 1.0018x over previous
//
#include <hip/hip_runtime.h>
#include <hip/hip_bf16.h>
#include <stdint.h>

#define B_D   384
#define B_E   2048
#define TOPK  50
#define LN_EPS 1e-5f
#define NKP   12            // physical packed K-steps of 64 (6 hi + 6 lo)
#define FIX_WINDOW 2e-4f

typedef short bf16x8 __attribute__((ext_vector_type(8)));
typedef float f32x4  __attribute__((ext_vector_type(4)));

// ---------------- wave helpers (wave64) ----------------
__device__ __forceinline__ float wave_sum_f(float v) {
#pragma unroll
    for (int d = 1; d < 64; d <<= 1) v += __shfl_xor(v, d, 64);
    return v;
}
__device__ __forceinline__ int wave_sum_i(int v) {
#pragma unroll
    for (int d = 1; d < 64; d <<= 1) v += __shfl_xor(v, d, 64);
    return v;
}
__device__ __forceinline__ float wave_max_f(float v) {
#pragma unroll
    for (int d = 1; d < 64; d <<= 1) v = fmaxf(v, __shfl_xor(v, d, 64));
    return v;
}

__device__ __forceinline__ ushort f2bf_hi(float v) {
    __hip_bfloat16 b = __float2bfloat16(v);
    return *(ushort*)&b;
}
__device__ __forceinline__ ushort f2bf_lo(float v) {
    __hip_bfloat16 b = __float2bfloat16(v);
    float rem = v - __bfloat162float(b);
    __hip_bfloat16 l = __float2bfloat16(rem);
    return *(ushort*)&l;
}

__device__ __forceinline__ void llds16(const void* g, void* l) {
    __builtin_amdgcn_global_load_lds((const __attribute__((address_space(1))) void*)g,
                                     (__attribute__((address_space(3))) void*)l, 16, 0, 0);
}

// ---------------- fused pack: A (mt=0..63) and B (y=64..71) tiles ----------------
__global__ __launch_bounds__(256) void pack_AB(
    const float* __restrict__ x, const float* __restrict__ We,
    ushort* __restrict__ Ap, ushort* __restrict__ Bp, int* __restrict__ cntr)
{
    const int ks = blockIdx.x, yb = blockIdx.y, t = threadIdx.x;
    if (cntr && t == 0 && ks == 0 && yb == 0) *cntr = 0;
    if (yb < 64) {
        const int mt = yb;
#pragma unroll
        for (int q = 0; q < 8; ++q) {
            const int s = q * 256 + t;          // 0..2047
            const int m = s & 255, kg = s >> 8;
            const int kp = ks * 64 + kg * 8;    // 0..767
            const int hi = (kp < 384);
            const int ksrc = hi ? kp : kp - 384;
            const float* src = x + (size_t)(mt * 256 + m) * B_D + ksrc;
            float4 v0 = *(const float4*)src;
            float4 v1 = *(const float4*)(src + 4);
            float vv[8] = {v0.x, v0.y, v0.z, v0.w, v1.x, v1.y, v1.z, v1.w};
            ushort o[8];
#pragma unroll
            for (int e = 0; e < 8; ++e)
                o[e] = hi ? f2bf_hi(vv[e]) : f2bf_lo(vv[e]);
            *(uint4*)(Ap + ((size_t)(mt * NKP + ks) * 2048 + s) * 8) = *(uint4*)o;
        }
    } else {
        const int nt = yb - 64;
#pragma unroll
        for (int q = 0; q < 8; ++q) {
            const int s = q * 256 + t;
            const int nl = s & 255, kg = s >> 8;
            const int kp = ks * 64 + kg * 8;
            const int hi = (kp < 384);
            const int ksrc = hi ? kp : kp - 384;
            const int ng = nt * 256 + nl;
            ushort o[8];
#pragma unroll
            for (int e = 0; e < 8; ++e) {
                float v = We[(size_t)(ksrc + e) * B_E + ng];
                o[e] = hi ? f2bf_hi(v) : f2bf_lo(v);
            }
            *(uint4*)(Bp + ((size_t)(nt * NKP + ks) * 2048 + s) * 8) = *(uint4*)o;
        }
    }
}

// ------- MFMA encoder GEMM, 256x256 tile, 2-phase dbuf, 3-products-per-stage -------
__global__ __launch_bounds__(512, 2) void enc_mfma256b(
    const ushort* __restrict__ Ap, const ushort* __restrict__ Bp,
    const float* __restrict__ be, float* __restrict__ y)
{
    __shared__ __align__(16) ushort Ah[2][8192];   // 2 x 16 KB
    __shared__ __align__(16) ushort Al[2][8192];
    __shared__ __align__(16) ushort Bh[2][8192];
    __shared__ __align__(16) ushort Bl[2][8192];
    const int t = threadIdx.x, lane = t & 63, w = t >> 6;
    const int wr = w >> 2, wc = w & 3;
    const int gid = blockIdx.x;
    const int swz = (gid & 7) * 64 + (gid >> 3);   // XCD-aware (512 % 8 == 0, bijective)
    const int nt = swz & 7, mt = swz >> 3;
    const ushort* gA = Ap + (size_t)mt * NKP * 16384;
    const ushort* gB = Bp + (size_t)nt * NKP * 16384;

    f32x4 acc[8][4];
#pragma unroll
    for (int i = 0; i < 8; ++i)
#pragma unroll
        for (int j = 0; j < 4; ++j)
#pragma unroll
            for (int r = 0; r < 4; ++r) acc[i][j][r] = 0.f;

    const int l15 = lane & 15, l4 = lane >> 4;

#define STAGEH(hk_, b_)                                                         \
    {                                                                           \
        const int hh = (hk_);                                                   \
        const int kt = hh >> 1, hf = hh & 1;                                    \
        const ushort* ah_ = gA + (size_t)kt * 16384 + hf * 8192 + t * 8;        \
        const ushort* al_ = gA + (size_t)(kt + 6) * 16384 + hf * 8192 + t * 8;  \
        const ushort* bh_ = gB + (size_t)kt * 16384 + hf * 8192 + t * 8;        \
        const ushort* bl_ = gB + (size_t)(kt + 6) * 16384 + hf * 8192 + t * 8;  \
        llds16(ah_,        &Ah[b_][t * 8]);                                     \
        llds16(ah_ + 4096, &Ah[b_][4096 + t * 8]);                              \
        llds16(al_,        &Al[b_][t * 8]);                                     \
        llds16(al_ + 4096, &Al[b_][4096 + t * 8]);                              \
        llds16(bh_,        &Bh[b_][t * 8]);                                     \
        llds16(bh_ + 4096, &Bh[b_][4096 + t * 8]);                              \
        llds16(bl_,        &Bl[b_][t * 8]);                                     \
        llds16(bl_ + 4096, &Bl[b_][4096 + t * 8]);                              \
    }

    STAGEH(0, 0);
    __syncthreads();                       // drains prologue stage

    for (int hk = 0; hk < 12; ++hk) {
        const int sl = hk & 1;
        if (hk + 1 < 12) STAGEH(hk + 1, sl ^ 1);
        bf16x8 bhf[4], ahf[8];
#pragma unroll
        for (int j = 0; j < 4; ++j)
            bhf[j] = *(const bf16x8*)&Bh[sl][(l4 * 256 + wc * 64 + j * 16 + l15) * 8];
#pragma unroll
        for (int i = 0; i < 8; ++i)
            ahf[i] = *(const bf16x8*)&Ah[sl][(l4 * 256 + wr * 128 + i * 16 + l15) * 8];
#pragma unroll
        for (int i = 0; i < 8; ++i)
#pragma unroll
            for (int j = 0; j < 4; ++j)
                acc[i][j] = __builtin_amdgcn_mfma_f32_16x16x32_bf16(ahf[i], bhf[j], acc[i][j], 0, 0, 0);
        bf16x8 blf[4];
#pragma unroll
        for (int j = 0; j < 4; ++j)
            blf[j] = *(const bf16x8*)&Bl[sl][(l4 * 256 + wc * 64 + j * 16 + l15) * 8];
#pragma unroll
        for (int i = 0; i < 8; ++i)
#pragma unroll
            for (int j = 0; j < 4; ++j)
                acc[i][j] = __builtin_amdgcn_mfma_f32_16x16x32_bf16(ahf[i], blf[j], acc[i][j], 0, 0, 0);
        bf16x8 alf[8];
#pragma unroll
        for (int i = 0; i < 8; ++i)
            alf[i] = *(const bf16x8*)&Al[sl][(l4 * 256 + wr * 128 + i * 16 + l15) * 8];
#pragma unroll
        for (int i = 0; i < 8; ++i)
#pragma unroll
            for (int j = 0; j < 4; ++j)
                acc[i][j] = __builtin_amdgcn_mfma_f32_16x16x32_bf16(alf[i], bhf[j], acc[i][j], 0, 0, 0);
        if (hk + 1 < 12) __syncthreads();  // frees slot sl for STAGE(hk+2)
    }
#undef STAGEH

    float bev[4];
#pragma unroll
    for (int j = 0; j < 4; ++j) bev[j] = be[nt * 256 + wc * 64 + j * 16 + l15];
#pragma unroll
    for (int i = 0; i < 8; ++i)
#pragma unroll
        for (int j = 0; j < 4; ++j)
#pragma unroll
            for (int r = 0; r < 4; ++r) {
                const int row = mt * 256 + wr * 128 + i * 16 + l4 * 4 + r;
                const int col = nt * 256 + wc * 64 + j * 16 + l15;
                y[(size_t)row * B_E + col] = acc[i][j][r] + bev[j];
            }
}

// ---------------- fp32 fallback GEMM ----------------
__global__ __launch_bounds__(256) void enc_gemm_f32(
    const float* __restrict__ x, const float* __restrict__ We,
    const float* __restrict__ be, float* __restrict__ y)
{
    __shared__ float As[8][128];
    __shared__ float Bs[8][128];
    const int t  = threadIdx.x;
    const int m0 = blockIdx.y * 128;
    const int n0 = blockIdx.x * 128;
    const int tx = t & 15, ty = t >> 4;
    const int la_m = t >> 1, la_k = (t & 1) * 4;
    const int lb_k = t >> 5, lb_c = (t & 31) * 4;

    float acc[8][8];
#pragma unroll
    for (int i = 0; i < 8; ++i)
#pragma unroll
        for (int j = 0; j < 8; ++j) acc[i][j] = 0.f;

    for (int k0 = 0; k0 < B_D; k0 += 8) {
        float4 a = *(const float4*)&x[(size_t)(m0 + la_m) * B_D + k0 + la_k];
        float4 b = *(const float4*)&We[(size_t)(k0 + lb_k) * B_E + n0 + lb_c];
        __syncthreads();
        As[la_k + 0][la_m] = a.x;
        As[la_k + 1][la_m] = a.y;
        As[la_k + 2][la_m] = a.z;
        As[la_k + 3][la_m] = a.w;
        *(float4*)&Bs[lb_k][lb_c] = b;
        __syncthreads();
#pragma unroll
        for (int kk = 0; kk < 8; ++kk) {
            float4 a0 = *(const float4*)&As[kk][ty * 4];
            float4 a1 = *(const float4*)&As[kk][ty * 4 + 64];
            float4 b0 = *(const float4*)&Bs[kk][tx * 4];
            float4 b1 = *(const float4*)&Bs[kk][tx * 4 + 64];
            float av[8] = {a0.x,a0.y,a0.z,a0.w,a1.x,a1.y,a1.z,a1.w};
            float bv[8] = {b0.x,b0.y,b0.z,b0.w,b1.x,b1.y,b1.z,b1.w};
#pragma unroll
            for (int i = 0; i < 8; ++i)
#pragma unroll
                for (int j = 0; j < 8; ++j)
                    acc[i][j] = fmaf(av[i], bv[j], acc[i][j]);
        }
    }
    float4 beL = *(const float4*)&be[n0 + tx * 4];
    float4 beH = *(const float4*)&be[n0 + 64 + tx * 4];
    float bl[8] = {beL.x,beL.y,beL.z,beL.w,beH.x,beH.y,beH.z,beH.w};
#pragma unroll
    for (int i = 0; i < 8; ++i) {
        int row = m0 + ty * 4 + (i & 3) + (i >> 2) * 64;
        float4 o0 = {acc[i][0]+bl[0], acc[i][1]+bl[1], acc[i][2]+bl[2], acc[i][3]+bl[3]};
        float4 o1 = {acc[i][4]+bl[4], acc[i][5]+bl[5], acc[i][6]+bl[6], acc[i][7]+bl[7]};
        *(float4*)&y[(size_t)row * B_E + n0 + tx * 4]      = o0;
        *(float4*)&y[(size_t)row * B_E + n0 + 64 + tx * 4] = o1;
    }
}

// ------- shared per-row LN -> relu -> exact top-50; returns ambiguity flag -------
__device__ __forceinline__ int ln_topk_row(
    float (&h)[32], int lane, const float* __restrict__ g1, const float* __restrict__ b1,
    float* __restrict__ row, int* __restrict__ IwR, float* __restrict__ VwR,
    float* __restrict__ ldsv, int* __restrict__ ldsi)
{
    float s = 0.f;
#pragma unroll
    for (int j = 0; j < 32; ++j) s += h[j];
    s = wave_sum_f(s);
    const float mu = s * (1.f / B_E);
    float ss = 0.f;
#pragma unroll
    for (int j = 0; j < 32; ++j) { float d = h[j] - mu; ss += d * d; }
    ss = wave_sum_f(ss);
    const float rstd = rsqrtf(ss * (1.f / B_E) + LN_EPS);
#pragma unroll
    for (int q = 0; q < 8; ++q) {
        float4 g  = *(const float4*)&g1[q * 256 + lane * 4];
        float4 bb = *(const float4*)&b1[q * 256 + lane * 4];
        float gg[4]  = {g.x,g.y,g.z,g.w};
        float bbv[4] = {bb.x,bb.y,bb.z,bb.w};
#pragma unroll
        for (int i = 0; i < 4; ++i) {
            int j = q*4+i;
            h[j] = fmaxf(fmaf((h[j] - mu) * rstd, gg[i], bbv[i]), 0.f);
        }
    }
    float mx = h[0];
#pragma unroll
    for (int j = 1; j < 32; ++j) mx = fmaxf(mx, h[j]);
    mx = wave_max_f(mx);

    // Phase 1: value-space bisection; invariant count(>=vlo) = cl >= TOPK.
    float vlo = 0.f, vhi = __uint_as_float(__float_as_uint(mx) + 1u);
    int cl = 2048;
    bool window = false;
    for (int it = 0; it < 20; ++it) {
        float mid = 0.5f * (vlo + vhi);
        if (it == 0 && 2.2f > vlo && 2.2f < vhi) mid = 2.2f;
        if (!(mid > vlo && mid < vhi)) break;
        int c = 0;
#pragma unroll
        for (int j = 0; j < 32; ++j)
            c += (int)__popcll(__ballot(h[j] >= mid));
        if (c >= TOPK) { vlo = mid; cl = c; if (c <= 64) { window = true; break; } }
        else vhi = mid;
    }
    unsigned lo = __float_as_uint(vlo);
    if (!window) {
        unsigned hi = __float_as_uint(vhi);
        while (hi - lo > 1u) {
            const unsigned mid = lo + ((hi - lo) >> 1);
            const float mf = __uint_as_float(mid);
            int c = 0;
#pragma unroll
            for (int j = 0; j < 32; ++j)
                c += (int)__popcll(__ballot(h[j] >= mf));
            if (c >= TOPK) { lo = mid; cl = c; if (c <= 64) break; }
            else hi = mid;
        }
    }
    const float T0 = __uint_as_float(lo);

    unsigned selmask = 0u;
    int flag = 0;
    bool fastSel = (cl <= 64 && T0 > 0.f);

    if (fastSel) {
        ldsv[lane] = -1.f;
        ldsi[lane] = 1 << 20;
        asm volatile("s_waitcnt lgkmcnt(0)" ::: "memory");
        int base = 0;
#pragma unroll
        for (int j = 0; j < 32; ++j) {
            const bool p = (h[j] >= T0);
            const unsigned long long m = __ballot(p);
            if (p) {
                const int pos = base + (int)__popcll(m & ((1ull << lane) - 1ull));
                ldsv[pos] = h[j];
                ldsi[pos] = (j >> 2) * 256 + lane * 4 + (j & 3);
            }
            base += (int)__popcll(m);
        }
        asm volatile("s_waitcnt lgkmcnt(0)" ::: "memory");
        float sv = ldsv[lane];
        int   si = ldsi[lane];
#pragma unroll
        for (int k = 2; k <= 64; k <<= 1) {
#pragma unroll
            for (int jj = k >> 1; jj > 0; jj >>= 1) {
                const float ov = __shfl_xor(sv, jj, 64);
                const int   oi = __shfl_xor(si, jj, 64);
                const bool dirUp = ((lane & k) == 0);
                const bool lower = ((lane & jj) == 0);
                const bool mineBefore = (sv > ov) || (sv == ov && si < oi);
                const bool keep = (lower == dirUp) ? mineBefore : !mineBefore;
                if (!keep) { sv = ov; si = oi; }
            }
        }
        const float T    = __shfl(sv, TOPK - 1, 64);
        const int   idxT = __shfl(si, TOPK - 1, 64);
        float v51;
        if (cl > TOPK) {
            v51 = __shfl(sv, TOPK, 64);
        } else {
            float bb = -1.f;
#pragma unroll
            for (int j = 0; j < 32; ++j) bb = (h[j] < T0) ? fmaxf(bb, h[j]) : bb;
            v51 = wave_max_f(bb);
        }
        flag = (T - v51 < FIX_WINDOW) ? 1 : 0;
#pragma unroll
        for (int j = 0; j < 32; ++j) {
            const int e = (j >> 2) * 256 + lane * 4 + (j & 3);
            if (h[j] > T || (h[j] == T && e <= idxT)) selmask |= (1u << j);
        }
        if (lane < TOPK) { IwR[lane] = si; VwR[lane] = sv; }
    } else {
        const float T = T0;
        int cgt = 0, ceq = 0;
        float below = -1.f;
#pragma unroll
        for (int j = 0; j < 32; ++j) {
            cgt += (h[j] > T); ceq += (h[j] == T);
            if (h[j] < T) below = fmaxf(below, h[j]);
        }
        const int cgt_t = wave_sum_i(cgt);
        const int ceq_t = wave_sum_i(ceq);
        below = wave_max_f(below);
        const int need = TOPK - cgt_t;

        if (cgt_t + ceq_t == TOPK) {
#pragma unroll
            for (int j = 0; j < 32; ++j) if (h[j] >= T) selmask |= (1u << j);
        } else {
            int base = 0;
            for (int q = 0; q < 8; ++q) {
                int tc = 0;
#pragma unroll
                for (int i = 0; i < 4; ++i) tc += (h[q*4+i] == T);
                int ip = tc;
#pragma unroll
                for (int d = 1; d < 64; d <<= 1) {
                    int o = __shfl_up(ip, d, 64);
                    if (lane >= d) ip += o;
                }
                int rk  = base + ip - tc;
                int tot = __shfl(ip, 63, 64);
#pragma unroll
                for (int i = 0; i < 4; ++i) {
                    int j = q*4+i;
                    if (h[j] > T) selmask |= (1u << j);
                    else if (h[j] == T) { if (rk < need) selmask |= (1u << j); rk++; }
                }
                base += tot;
            }
        }
        if (T > 0.f) {
            if (cgt_t + ceq_t != TOPK && ceq_t > need) flag = 1;
            else if (T - below < FIX_WINDOW) flag = 1;
        }
        const int myc = __popc(selmask);
        int ip = myc;
#pragma unroll
        for (int d = 1; d < 64; d <<= 1) {
            int o = __shfl_up(ip, d, 64);
            if (lane >= d) ip += o;
        }
        int pos = ip - myc;
        for (int j = 0; j < 32; ++j) {
            if ((selmask >> j) & 1u) {
                int e = (j >> 2) * 256 + lane * 4 + (j & 3);
                IwR[pos] = e;
                VwR[pos] = h[j];
                pos++;
            }
        }
    }

#pragma unroll
    for (int q = 0; q < 8; ++q) {
        float4 o;
        o.x = ((selmask >> (q*4+0)) & 1u) ? h[q*4+0] : 0.f;
        o.y = ((selmask >> (q*4+1)) & 1u) ? h[q*4+1] : 0.f;
        o.z = ((selmask >> (q*4+2)) & 1u) ? h[q*4+2] : 0.f;
        o.w = ((selmask >> (q*4+3)) & 1u) ? h[q*4+3] : 0.f;
        *(float4*)&row[q * 256 + lane * 4] = o;
    }
    return flag;
}

// ------- topk (blocks 0..nTopk-1) fused with pack_W (blocks nTopk..nTopk+1023) -------
__global__ __launch_bounds__(256) void topk_packW(
    float* __restrict__ y, const float* __restrict__ g1, const float* __restrict__ b1,
    int* __restrict__ Iw, float* __restrict__ Vw,
    int* __restrict__ rowlist, int* __restrict__ cntr,
    const float* __restrict__ Wd, const float* __restrict__ Wb, uint* __restrict__ Wp,
    int nTopk)
{
    __shared__ float ldsv[4][64];
    __shared__ int   ldsi[4][64];
    const int bid = blockIdx.x;
    const int t = threadIdx.x;
    if (bid >= nTopk) {
        const int e = (bid - nTopk) * 2 + (t >> 7);
        const int tt = t & 127;
#pragma unroll
        for (int j = 0; j < 3; ++j) {
            const int c = tt + 128 * j;
            const ushort d = f2bf_hi(Wd[(size_t)e * B_D + c]);
            const ushort b = f2bf_hi(Wb[(size_t)e * B_D + c]);
            Wp[(size_t)e * B_D + c] = ((uint)b << 16) | (uint)d;
        }
        return;
    }
    const int lane = t & 63;
    const int w = t >> 6;
    const int r = bid * 4 + w;
    float* row = y + (size_t)r * B_E;
    float h[32];
#pragma unroll
    for (int q = 0; q < 8; ++q) {
        float4 v = *(const float4*)&row[q * 256 + lane * 4];
        h[q*4+0] = v.x; h[q*4+1] = v.y; h[q*4+2] = v.z; h[q*4+3] = v.w;
    }
    int flag = ln_topk_row(h, lane, g1, b1, row, Iw + r * TOPK, Vw + r * TOPK,
                           ldsv[w], ldsi[w]);
    if (rowlist && lane == 0 && flag) {
        int p = atomicAdd(cntr, 1);
        rowlist[p] = r;
    }
}

// ------- fixup phase 1: exact fp32 recompute of flagged rows (grid-stride batches) -------
// Per-column arithmetic bit-identical: acc = be[c]; fmaf ascending k.
__global__ __launch_bounds__(256) void fixup_recompute(
    const float* __restrict__ x, const float* __restrict__ We, const float* __restrict__ be,
    float* __restrict__ y, const int* __restrict__ rowlist, const int* __restrict__ cntr)
{
    const int nflag = *cntr;
    const int t = threadIdx.x;
    __shared__ float xs[8][B_D];
    __shared__ int   rIdx[8];

    for (int rb = blockIdx.y * 8; rb < nflag; rb += gridDim.y * 8) {
        const int nact = min(nflag - rb, 8);
        __syncthreads();   // protect xs/rIdx reuse across iterations
        if (t < 8) rIdx[t] = (t < nact) ? rowlist[rb + t] : -1;
        __syncthreads();
#pragma unroll
        for (int i = 0; i < 8; ++i) {
            if (i < nact) {
                const float* src = x + (size_t)rIdx[i] * B_D;
                for (int j = t; j < B_D; j += 256) xs[i][j] = src[j];
            } else {
                for (int j = t; j < B_D; j += 256) xs[i][j] = 0.f;
            }
        }
        __syncthreads();

        const int c = blockIdx.x * 256 + t;
        const float bc = be[c];
        float acc[8];
#pragma unroll
        for (int i = 0; i < 8; ++i) acc[i] = bc;
#pragma unroll 4
        for (int k = 0; k < B_D; ++k) {
            const float w = We[(size_t)k * B_E + c];
#pragma unroll
            for (int i = 0; i < 8; ++i) acc[i] = fmaf(xs[i][k], w, acc[i]);
        }
#pragma unroll
        for (int i = 0; i < 8; ++i)
            if (i < nact) y[(size_t)rIdx[i] * B_E + c] = acc[i];
    }
}

// ------- fixup phase 2: redo LN+topk on flagged rows (rowlist-driven) -------
__global__ __launch_bounds__(256) void fixup_select(
    float* __restrict__ y, const float* __restrict__ g1, const float* __restrict__ b1,
    int* __restrict__ Iw, float* __restrict__ Vw,
    const int* __restrict__ rowlist, const int* __restrict__ cntr)
{
    __shared__ float ldsv[4][64];
    __shared__ int   ldsi[4][64];
    const int nflag = *cntr;
    const int w = threadIdx.x >> 6;
    const int lane = threadIdx.x & 63;
    for (int i = blockIdx.x * 4 + w; i < nflag; i += gridDim.x * 4) {
        const int r = rowlist[i];
        float* row = y + (size_t)r * B_E;
        float h[32];
#pragma unroll
        for (int q = 0; q < 8; ++q) {
            float4 v = *(const float4*)&row[q * 256 + lane * 4];
            h[q*4+0] = v.x; h[q*4+1] = v.y; h[q*4+2] = v.z; h[q*4+3] = v.w;
        }
        ln_topk_row(h, lane, g1, b1, row, Iw + r * TOPK, Vw + r * TOPK,
                    ldsv[w], ldsi[w]);
    }
}

// ---- decode (packed bf16 weights): 4 rows per 512-thread block; per-row chain
// identical to the verified single-row decode (bit-identical outputs). ----
__global__ __launch_bounds__(512) void decode_packed4(
    const int* __restrict__ Iw, const float* __restrict__ Vw,
    const uint* __restrict__ Wp, const float* __restrict__ bd,
    const float* __restrict__ bbias, const float* __restrict__ g2,
    const float* __restrict__ b2, float* __restrict__ recon, float* __restrict__ sep)
{
    __shared__ int   sI[4][TOPK];
    __shared__ float sV[4][TOPK];
    __shared__ float red[4][2];
    const int q = threadIdx.x >> 7;        // row group 0..3
    const int t = threadIdx.x & 127;
    const int r = blockIdx.x * 4 + q;
    if (t < TOPK) { sI[q][t] = Iw[r * TOPK + t]; sV[q][t] = Vw[r * TOPK + t]; }
    __syncthreads();
    float ad[3], ab[3];
#pragma unroll
    for (int j = 0; j < 3; ++j) { ad[j] = bd[t + 128*j]; ab[j] = bbias[t + 128*j]; }
#pragma unroll 2
    for (int i = 0; i < TOPK; ++i) {
        const int   idx = sI[q][i];
        const float v   = sV[q][i];
        const uint* wp  = Wp + (size_t)idx * B_D;
#pragma unroll
        for (int j = 0; j < 3; ++j) {
            const uint u = wp[t + 128*j];
            const float wd = __uint_as_float(u << 16);
            const float wb = __uint_as_float(u & 0xFFFF0000u);
            ad[j] = fmaf(v, wd, ad[j]);
            ab[j] = fmaf(v, wb, ab[j]);
        }
    }
#pragma unroll
    for (int j = 0; j < 3; ++j) recon[(size_t)r * B_D + t + 128*j] = ad[j];
    float s = ab[0] + ab[1] + ab[2];
    s = wave_sum_f(s);
    if ((t & 63) == 0) red[q][t >> 6] = s;
    __syncthreads();
    const float mu = (red[q][0] + red[q][1]) * (1.f / B_D);
    __syncthreads();
    float ss = 0.f;
#pragma unroll
    for (int j = 0; j < 3; ++j) { float d = ab[j] - mu; ss += d * d; }
    ss = wave_sum_f(ss);
    if ((t & 63) == 0) red[q][t >> 6] = ss;
    __syncthreads();
    const float rstd = rsqrtf((red[q][0] + red[q][1]) * (1.f / B_D) + LN_EPS);
#pragma unroll
    for (int j = 0; j < 3; ++j) {
        int c = t + 128*j;
        sep[(size_t)r * B_D + c] = fmaf((ab[j] - mu) * rstd, g2[c], b2[c]);
    }
}

// -------- decode (f32 weights) — fallback only --------
__global__ __launch_bounds__(128) void decode_f32(
    const int* __restrict__ Iw, const float* __restrict__ Vw,
    const float* __restrict__ Wd, const float* __restrict__ bd,
    const float* __restrict__ Wb, const float* __restrict__ bbias,
    const float* __restrict__ g2, const float* __restrict__ b2,
    float* __restrict__ recon, float* __restrict__ sep)
{
    __shared__ int   sI[TOPK];
    __shared__ float sV[TOPK];
    __shared__ float red[2];
    const int r = blockIdx.x, t = threadIdx.x;
    if (t < TOPK) { sI[t] = Iw[r * TOPK + t]; sV[t] = Vw[r * TOPK + t]; }
    __syncthreads();
    float ad[3], ab[3];
#pragma unroll
    for (int j = 0; j < 3; ++j) { ad[j] = bd[t + 128*j]; ab[j] = bbias[t + 128*j]; }
#pragma unroll 2
    for (int i = 0; i < TOPK; ++i) {
        const int   idx = sI[i];
        const float v   = sV[i];
        const float* wd = Wd + (size_t)idx * B_D;
        const float* wb = Wb + (size_t)idx * B_D;
#pragma unroll
        for (int j = 0; j < 3; ++j) {
            ad[j] = fmaf(v, wd[t + 128*j], ad[j]);
            ab[j] = fmaf(v, wb[t + 128*j], ab[j]);
        }
    }
#pragma unroll
    for (int j = 0; j < 3; ++j) recon[(size_t)r * B_D + t + 128*j] = ad[j];
    float s = ab[0] + ab[1] + ab[2];
    s = wave_sum_f(s);
    if ((t & 63) == 0) red[t >> 6] = s;
    __syncthreads();
    const float mu = (red[0] + red[1]) * (1.f / B_D);
    __syncthreads();
    float ss = 0.f;
#pragma unroll
    for (int j = 0; j < 3; ++j) { float d = ab[j] - mu; ss += d * d; }
    ss = wave_sum_f(ss);
    if ((t & 63) == 0) red[t >> 6] = ss;
    __syncthreads();
    const float rstd = rsqrtf((red[0] + red[1]) * (1.f / B_D) + LN_EPS);
#pragma unroll
    for (int j = 0; j < 3; ++j) {
        int c = t + 128*j;
        sep[(size_t)r * B_D + c] = fmaf((ab[j] - mu) * rstd, g2[c], b2[c]);
    }
}

// ------- fallback topk (no fixup machinery) -------
__global__ __launch_bounds__(256) void topk_only(
    float* __restrict__ y, const float* __restrict__ g1, const float* __restrict__ b1,
    int* __restrict__ Iw, float* __restrict__ Vw)
{
    __shared__ float ldsv[4][64];
    __shared__ int   ldsi[4][64];
    const int lane = threadIdx.x & 63;
    const int w = threadIdx.x >> 6;
    const int r = blockIdx.x * 4 + w;
    float* row = y + (size_t)r * B_E;
    float h[32];
#pragma unroll
    for (int q = 0; q < 8; ++q) {
        float4 v = *(const float4*)&row[q * 256 + lane * 4];
        h[q*4+0] = v.x; h[q*4+1] = v.y; h[q*4+2] = v.z; h[q*4+3] = v.w;
    }
    ln_topk_row(h, lane, g1, b1, row, Iw + r * TOPK, Vw + r * TOPK, ldsv[w], ldsi[w]);
}

extern "C" void kernel_launch(void* const* d_in, const int* in_sizes, int n_in,
                              void* d_out, int out_size, void* d_ws, size_t ws_size,
                              hipStream_t stream)
{
    const float* x  = (const float*)d_in[0];
    const float* We = (const float*)d_in[1];
    const float* be = (const float*)d_in[2];
    const float* g1 = (const float*)d_in[3];
    const float* b1 = (const float*)d_in[4];
    const float* Wd = (const float*)d_in[5];
    const float* bd = (const float*)d_in[6];
    const float* Wb = (const float*)d_in[7];
    const float* bb = (const float*)d_in[8];
    const float* g2 = (const float*)d_in[9];
    const float* b2 = (const float*)d_in[10];

    const int Brows = in_sizes[0] / B_D;               // 16384
    float* recon  = (float*)d_out;
    float* sparse = recon + (size_t)Brows * B_D;       // [B,2048]
    float* sep    = sparse + (size_t)Brows * B_E;

    char* ws = (char*)d_ws;
    int*   Iw      = (int*)ws;                         // 3,276,800
    float* Vw      = (float*)(ws + 3276800);           // 3,276,800
    int*   rowlist = (int*)(ws + 6619136);             // 65,536
    int*   cntr    = (int*)(ws + 6684672);             // 64 (padded)
    const size_t apOff = 6688768;                      // Ap: 25,165,824 (aliased by Wp after enc)
    const size_t bpOff = apOff + (size_t)64 * NKP * 2048 * 16;
    const size_t need  = bpOff + (size_t)8 * NKP * 2048 * 16;    // ~35.0 MB

    if (ws_size >= need) {
        ushort* Ap = (ushort*)(ws + apOff);
        ushort* Bp = (ushort*)(ws + bpOff);
        uint*   Wp = (uint*)(ws + apOff);              // aliases Ap (enc done before pack_W blocks)
        pack_AB<<<dim3(NKP, 72), dim3(256), 0, stream>>>(x, We, Ap, Bp, cntr);
        enc_mfma256b<<<dim3(512), dim3(512), 0, stream>>>(Ap, Bp, be, sparse);
        topk_packW<<<dim3(Brows / 4 + 1024), dim3(256), 0, stream>>>(
            sparse, g1, b1, Iw, Vw, rowlist, cntr, Wd, Wb, Wp, Brows / 4);
        fixup_recompute<<<dim3(8, 64), dim3(256), 0, stream>>>(x, We, be, sparse, rowlist, cntr);
        fixup_select<<<dim3(256), dim3(256), 0, stream>>>(sparse, g1, b1, Iw, Vw, rowlist, cntr);
        decode_packed4<<<dim3(Brows / 4), dim3(512), 0, stream>>>(Iw, Vw, Wp, bd, bb, g2, b2, recon, sep);
    } else {
        enc_gemm_f32<<<dim3(16, 128), dim3(256), 0, stream>>>(x, We, be, sparse);
        topk_only<<<dim3(Brows / 4), dim3(256), 0, stream>>>(sparse, g1, b1, Iw, Vw);
        decode_f32<<<dim3(Brows), dim3(128), 0, stream>>>(Iw, Vw, Wd, bd, Wb, bb, g2, b2, recon, sep);
    }
}

// Round 15
// 258.463 us; speedup vs baseline: 1.1240x; 1.0323x over previous
//
#include <hip/hip_runtime.h>
#include <hip/hip_bf16.h>
#include <stdint.h>

#define B_D   384
#define B_E   2048
#define TOPK  50
#define LN_EPS 1e-5f
#define NKP   12            // physical packed K-steps of 64 (6 hi + 6 lo)
#define FIX_WINDOW 2e-4f

typedef short bf16x8 __attribute__((ext_vector_type(8)));
typedef float f32x4  __attribute__((ext_vector_type(4)));

// ---------------- wave helpers (wave64) ----------------
__device__ __forceinline__ float wave_sum_f(float v) {
#pragma unroll
    for (int d = 1; d < 64; d <<= 1) v += __shfl_xor(v, d, 64);
    return v;
}
__device__ __forceinline__ int wave_sum_i(int v) {
#pragma unroll
    for (int d = 1; d < 64; d <<= 1) v += __shfl_xor(v, d, 64);
    return v;
}
__device__ __forceinline__ float wave_max_f(float v) {
#pragma unroll
    for (int d = 1; d < 64; d <<= 1) v = fmaxf(v, __shfl_xor(v, d, 64));
    return v;
}

__device__ __forceinline__ ushort f2bf_hi(float v) {
    __hip_bfloat16 b = __float2bfloat16(v);
    return *(ushort*)&b;
}
__device__ __forceinline__ ushort f2bf_lo(float v) {
    __hip_bfloat16 b = __float2bfloat16(v);
    float rem = v - __bfloat162float(b);
    __hip_bfloat16 l = __float2bfloat16(rem);
    return *(ushort*)&l;
}

__device__ __forceinline__ void llds16(const void* g, void* l) {
    __builtin_amdgcn_global_load_lds((const __attribute__((address_space(1))) void*)g,
                                     (__attribute__((address_space(3))) void*)l, 16, 0, 0);
}

// ---------------- fused pack: A (mt=0..63) and B (y=64..71) tiles ----------------
__global__ __launch_bounds__(256) void pack_AB(
    const float* __restrict__ x, const float* __restrict__ We,
    ushort* __restrict__ Ap, ushort* __restrict__ Bp, int* __restrict__ cntr)
{
    const int ks = blockIdx.x, yb = blockIdx.y, t = threadIdx.x;
    if (cntr && t == 0 && ks == 0 && yb == 0) *cntr = 0;
    if (yb < 64) {
        const int mt = yb;
#pragma unroll
        for (int q = 0; q < 8; ++q) {
            const int s = q * 256 + t;          // 0..2047
            const int m = s & 255, kg = s >> 8;
            const int kp = ks * 64 + kg * 8;    // 0..767
            const int hi = (kp < 384);
            const int ksrc = hi ? kp : kp - 384;
            const float* src = x + (size_t)(mt * 256 + m) * B_D + ksrc;
            float4 v0 = *(const float4*)src;
            float4 v1 = *(const float4*)(src + 4);
            float vv[8] = {v0.x, v0.y, v0.z, v0.w, v1.x, v1.y, v1.z, v1.w};
            ushort o[8];
#pragma unroll
            for (int e = 0; e < 8; ++e)
                o[e] = hi ? f2bf_hi(vv[e]) : f2bf_lo(vv[e]);
            *(uint4*)(Ap + ((size_t)(mt * NKP + ks) * 2048 + s) * 8) = *(uint4*)o;
        }
    } else {
        const int nt = yb - 64;
#pragma unroll
        for (int q = 0; q < 8; ++q) {
            const int s = q * 256 + t;
            const int nl = s & 255, kg = s >> 8;
            const int kp = ks * 64 + kg * 8;
            const int hi = (kp < 384);
            const int ksrc = hi ? kp : kp - 384;
            const int ng = nt * 256 + nl;
            ushort o[8];
#pragma unroll
            for (int e = 0; e < 8; ++e) {
                float v = We[(size_t)(ksrc + e) * B_E + ng];
                o[e] = hi ? f2bf_hi(v) : f2bf_lo(v);
            }
            *(uint4*)(Bp + ((size_t)(nt * NKP + ks) * 2048 + s) * 8) = *(uint4*)o;
        }
    }
}

// ------- MFMA encoder GEMM, 256x256 tile, 2-phase dbuf, 3-products-per-stage -------
__global__ __launch_bounds__(512, 2) void enc_mfma256b(
    const ushort* __restrict__ Ap, const ushort* __restrict__ Bp,
    const float* __restrict__ be, float* __restrict__ y)
{
    __shared__ __align__(16) ushort Ah[2][8192];   // 2 x 16 KB
    __shared__ __align__(16) ushort Al[2][8192];
    __shared__ __align__(16) ushort Bh[2][8192];
    __shared__ __align__(16) ushort Bl[2][8192];
    const int t = threadIdx.x, lane = t & 63, w = t >> 6;
    const int wr = w >> 2, wc = w & 3;
    const int gid = blockIdx.x;
    const int swz = (gid & 7) * 64 + (gid >> 3);   // XCD-aware (512 % 8 == 0, bijective)
    const int nt = swz & 7, mt = swz >> 3;
    const ushort* gA = Ap + (size_t)mt * NKP * 16384;
    const ushort* gB = Bp + (size_t)nt * NKP * 16384;

    f32x4 acc[8][4];
#pragma unroll
    for (int i = 0; i < 8; ++i)
#pragma unroll
        for (int j = 0; j < 4; ++j)
#pragma unroll
            for (int r = 0; r < 4; ++r) acc[i][j][r] = 0.f;

    const int l15 = lane & 15, l4 = lane >> 4;

#define STAGEH(hk_, b_)                                                         \
    {                                                                           \
        const int hh = (hk_);                                                   \
        const int kt = hh >> 1, hf = hh & 1;                                    \
        const ushort* ah_ = gA + (size_t)kt * 16384 + hf * 8192 + t * 8;        \
        const ushort* al_ = gA + (size_t)(kt + 6) * 16384 + hf * 8192 + t * 8;  \
        const ushort* bh_ = gB + (size_t)kt * 16384 + hf * 8192 + t * 8;        \
        const ushort* bl_ = gB + (size_t)(kt + 6) * 16384 + hf * 8192 + t * 8;  \
        llds16(ah_,        &Ah[b_][t * 8]);                                     \
        llds16(ah_ + 4096, &Ah[b_][4096 + t * 8]);                              \
        llds16(al_,        &Al[b_][t * 8]);                                     \
        llds16(al_ + 4096, &Al[b_][4096 + t * 8]);                              \
        llds16(bh_,        &Bh[b_][t * 8]);                                     \
        llds16(bh_ + 4096, &Bh[b_][4096 + t * 8]);                              \
        llds16(bl_,        &Bl[b_][t * 8]);                                     \
        llds16(bl_ + 4096, &Bl[b_][4096 + t * 8]);                              \
    }

    STAGEH(0, 0);
    __syncthreads();                       // drains prologue stage

    for (int hk = 0; hk < 12; ++hk) {
        const int sl = hk & 1;
        if (hk + 1 < 12) STAGEH(hk + 1, sl ^ 1);
        bf16x8 bhf[4], ahf[8];
#pragma unroll
        for (int j = 0; j < 4; ++j)
            bhf[j] = *(const bf16x8*)&Bh[sl][(l4 * 256 + wc * 64 + j * 16 + l15) * 8];
#pragma unroll
        for (int i = 0; i < 8; ++i)
            ahf[i] = *(const bf16x8*)&Ah[sl][(l4 * 256 + wr * 128 + i * 16 + l15) * 8];
#pragma unroll
        for (int i = 0; i < 8; ++i)
#pragma unroll
            for (int j = 0; j < 4; ++j)
                acc[i][j] = __builtin_amdgcn_mfma_f32_16x16x32_bf16(ahf[i], bhf[j], acc[i][j], 0, 0, 0);
        bf16x8 blf[4];
#pragma unroll
        for (int j = 0; j < 4; ++j)
            blf[j] = *(const bf16x8*)&Bl[sl][(l4 * 256 + wc * 64 + j * 16 + l15) * 8];
#pragma unroll
        for (int i = 0; i < 8; ++i)
#pragma unroll
            for (int j = 0; j < 4; ++j)
                acc[i][j] = __builtin_amdgcn_mfma_f32_16x16x32_bf16(ahf[i], blf[j], acc[i][j], 0, 0, 0);
        bf16x8 alf[8];
#pragma unroll
        for (int i = 0; i < 8; ++i)
            alf[i] = *(const bf16x8*)&Al[sl][(l4 * 256 + wr * 128 + i * 16 + l15) * 8];
#pragma unroll
        for (int i = 0; i < 8; ++i)
#pragma unroll
            for (int j = 0; j < 4; ++j)
                acc[i][j] = __builtin_amdgcn_mfma_f32_16x16x32_bf16(alf[i], bhf[j], acc[i][j], 0, 0, 0);
        if (hk + 1 < 12) __syncthreads();  // frees slot sl for STAGE(hk+2)
    }
#undef STAGEH

    float bev[4];
#pragma unroll
    for (int j = 0; j < 4; ++j) bev[j] = be[nt * 256 + wc * 64 + j * 16 + l15];
#pragma unroll
    for (int i = 0; i < 8; ++i)
#pragma unroll
        for (int j = 0; j < 4; ++j)
#pragma unroll
            for (int r = 0; r < 4; ++r) {
                const int row = mt * 256 + wr * 128 + i * 16 + l4 * 4 + r;
                const int col = nt * 256 + wc * 64 + j * 16 + l15;
                y[(size_t)row * B_E + col] = acc[i][j][r] + bev[j];
            }
}

// ---------------- fp32 fallback GEMM ----------------
__global__ __launch_bounds__(256) void enc_gemm_f32(
    const float* __restrict__ x, const float* __restrict__ We,
    const float* __restrict__ be, float* __restrict__ y)
{
    __shared__ float As[8][128];
    __shared__ float Bs[8][128];
    const int t  = threadIdx.x;
    const int m0 = blockIdx.y * 128;
    const int n0 = blockIdx.x * 128;
    const int tx = t & 15, ty = t >> 4;
    const int la_m = t >> 1, la_k = (t & 1) * 4;
    const int lb_k = t >> 5, lb_c = (t & 31) * 4;

    float acc[8][8];
#pragma unroll
    for (int i = 0; i < 8; ++i)
#pragma unroll
        for (int j = 0; j < 8; ++j) acc[i][j] = 0.f;

    for (int k0 = 0; k0 < B_D; k0 += 8) {
        float4 a = *(const float4*)&x[(size_t)(m0 + la_m) * B_D + k0 + la_k];
        float4 b = *(const float4*)&We[(size_t)(k0 + lb_k) * B_E + n0 + lb_c];
        __syncthreads();
        As[la_k + 0][la_m] = a.x;
        As[la_k + 1][la_m] = a.y;
        As[la_k + 2][la_m] = a.z;
        As[la_k + 3][la_m] = a.w;
        *(float4*)&Bs[lb_k][lb_c] = b;
        __syncthreads();
#pragma unroll
        for (int kk = 0; kk < 8; ++kk) {
            float4 a0 = *(const float4*)&As[kk][ty * 4];
            float4 a1 = *(const float4*)&As[kk][ty * 4 + 64];
            float4 b0 = *(const float4*)&Bs[kk][tx * 4];
            float4 b1 = *(const float4*)&Bs[kk][tx * 4 + 64];
            float av[8] = {a0.x,a0.y,a0.z,a0.w,a1.x,a1.y,a1.z,a1.w};
            float bv[8] = {b0.x,b0.y,b0.z,b0.w,b1.x,b1.y,b1.z,b1.w};
#pragma unroll
            for (int i = 0; i < 8; ++i)
#pragma unroll
                for (int j = 0; j < 8; ++j)
                    acc[i][j] = fmaf(av[i], bv[j], acc[i][j]);
        }
    }
    float4 beL = *(const float4*)&be[n0 + tx * 4];
    float4 beH = *(const float4*)&be[n0 + 64 + tx * 4];
    float bl[8] = {beL.x,beL.y,beL.z,beL.w,beH.x,beH.y,beH.z,beH.w};
#pragma unroll
    for (int i = 0; i < 8; ++i) {
        int row = m0 + ty * 4 + (i & 3) + (i >> 2) * 64;
        float4 o0 = {acc[i][0]+bl[0], acc[i][1]+bl[1], acc[i][2]+bl[2], acc[i][3]+bl[3]};
        float4 o1 = {acc[i][4]+bl[4], acc[i][5]+bl[5], acc[i][6]+bl[6], acc[i][7]+bl[7]};
        *(float4*)&y[(size_t)row * B_E + n0 + tx * 4]      = o0;
        *(float4*)&y[(size_t)row * B_E + n0 + 64 + tx * 4] = o1;
    }
}

// ------- shared per-row LN -> relu -> exact top-50; returns ambiguity flag -------
// Also mirrors the final (idx,val) selection into ldsv/ldsi[0..49] (same order
// as the IwR/VwR writes) so a caller can consume the selection in-wave.
__device__ __forceinline__ int ln_topk_row(
    float (&h)[32], int lane, const float* __restrict__ g1, const float* __restrict__ b1,
    float* __restrict__ row, int* __restrict__ IwR, float* __restrict__ VwR,
    float* __restrict__ ldsv, int* __restrict__ ldsi)
{
    float s = 0.f;
#pragma unroll
    for (int j = 0; j < 32; ++j) s += h[j];
    s = wave_sum_f(s);
    const float mu = s * (1.f / B_E);
    float ss = 0.f;
#pragma unroll
    for (int j = 0; j < 32; ++j) { float d = h[j] - mu; ss += d * d; }
    ss = wave_sum_f(ss);
    const float rstd = rsqrtf(ss * (1.f / B_E) + LN_EPS);
#pragma unroll
    for (int q = 0; q < 8; ++q) {
        float4 g  = *(const float4*)&g1[q * 256 + lane * 4];
        float4 bb = *(const float4*)&b1[q * 256 + lane * 4];
        float gg[4]  = {g.x,g.y,g.z,g.w};
        float bbv[4] = {bb.x,bb.y,bb.z,bb.w};
#pragma unroll
        for (int i = 0; i < 4; ++i) {
            int j = q*4+i;
            h[j] = fmaxf(fmaf((h[j] - mu) * rstd, gg[i], bbv[i]), 0.f);
        }
    }
    float mx = h[0];
#pragma unroll
    for (int j = 1; j < 32; ++j) mx = fmaxf(mx, h[j]);
    mx = wave_max_f(mx);

    // Phase 1: value-space bisection; invariant count(>=vlo) = cl >= TOPK.
    float vlo = 0.f, vhi = __uint_as_float(__float_as_uint(mx) + 1u);
    int cl = 2048;
    bool window = false;
    for (int it = 0; it < 20; ++it) {
        float mid = 0.5f * (vlo + vhi);
        if (it == 0 && 2.2f > vlo && 2.2f < vhi) mid = 2.2f;
        if (!(mid > vlo && mid < vhi)) break;
        int c = 0;
#pragma unroll
        for (int j = 0; j < 32; ++j)
            c += (int)__popcll(__ballot(h[j] >= mid));
        if (c >= TOPK) { vlo = mid; cl = c; if (c <= 64) { window = true; break; } }
        else vhi = mid;
    }
    unsigned lo = __float_as_uint(vlo);
    if (!window) {
        unsigned hi = __float_as_uint(vhi);
        while (hi - lo > 1u) {
            const unsigned mid = lo + ((hi - lo) >> 1);
            const float mf = __uint_as_float(mid);
            int c = 0;
#pragma unroll
            for (int j = 0; j < 32; ++j)
                c += (int)__popcll(__ballot(h[j] >= mf));
            if (c >= TOPK) { lo = mid; cl = c; if (c <= 64) break; }
            else hi = mid;
        }
    }
    const float T0 = __uint_as_float(lo);

    unsigned selmask = 0u;
    int flag = 0;
    bool fastSel = (cl <= 64 && T0 > 0.f);

    if (fastSel) {
        ldsv[lane] = -1.f;
        ldsi[lane] = 1 << 20;
        asm volatile("s_waitcnt lgkmcnt(0)" ::: "memory");
        int base = 0;
#pragma unroll
        for (int j = 0; j < 32; ++j) {
            const bool p = (h[j] >= T0);
            const unsigned long long m = __ballot(p);
            if (p) {
                const int pos = base + (int)__popcll(m & ((1ull << lane) - 1ull));
                ldsv[pos] = h[j];
                ldsi[pos] = (j >> 2) * 256 + lane * 4 + (j & 3);
            }
            base += (int)__popcll(m);
        }
        asm volatile("s_waitcnt lgkmcnt(0)" ::: "memory");
        float sv = ldsv[lane];
        int   si = ldsi[lane];
#pragma unroll
        for (int k = 2; k <= 64; k <<= 1) {
#pragma unroll
            for (int jj = k >> 1; jj > 0; jj >>= 1) {
                const float ov = __shfl_xor(sv, jj, 64);
                const int   oi = __shfl_xor(si, jj, 64);
                const bool dirUp = ((lane & k) == 0);
                const bool lower = ((lane & jj) == 0);
                const bool mineBefore = (sv > ov) || (sv == ov && si < oi);
                const bool keep = (lower == dirUp) ? mineBefore : !mineBefore;
                if (!keep) { sv = ov; si = oi; }
            }
        }
        const float T    = __shfl(sv, TOPK - 1, 64);
        const int   idxT = __shfl(si, TOPK - 1, 64);
        float v51;
        if (cl > TOPK) {
            v51 = __shfl(sv, TOPK, 64);
        } else {
            float bb = -1.f;
#pragma unroll
            for (int j = 0; j < 32; ++j) bb = (h[j] < T0) ? fmaxf(bb, h[j]) : bb;
            v51 = wave_max_f(bb);
        }
        flag = (T - v51 < FIX_WINDOW) ? 1 : 0;
#pragma unroll
        for (int j = 0; j < 32; ++j) {
            const int e = (j >> 2) * 256 + lane * 4 + (j & 3);
            if (h[j] > T || (h[j] == T && e <= idxT)) selmask |= (1u << j);
        }
        if (lane < TOPK) { IwR[lane] = si; VwR[lane] = sv; }
        // mirror selection (sorted order, matches IwR layout)
        ldsv[lane] = sv;
        ldsi[lane] = si;
    } else {
        const float T = T0;
        int cgt = 0, ceq = 0;
        float below = -1.f;
#pragma unroll
        for (int j = 0; j < 32; ++j) {
            cgt += (h[j] > T); ceq += (h[j] == T);
            if (h[j] < T) below = fmaxf(below, h[j]);
        }
        const int cgt_t = wave_sum_i(cgt);
        const int ceq_t = wave_sum_i(ceq);
        below = wave_max_f(below);
        const int need = TOPK - cgt_t;

        if (cgt_t + ceq_t == TOPK) {
#pragma unroll
            for (int j = 0; j < 32; ++j) if (h[j] >= T) selmask |= (1u << j);
        } else {
            int base = 0;
            for (int q = 0; q < 8; ++q) {
                int tc = 0;
#pragma unroll
                for (int i = 0; i < 4; ++i) tc += (h[q*4+i] == T);
                int ip = tc;
#pragma unroll
                for (int d = 1; d < 64; d <<= 1) {
                    int o = __shfl_up(ip, d, 64);
                    if (lane >= d) ip += o;
                }
                int rk  = base + ip - tc;
                int tot = __shfl(ip, 63, 64);
#pragma unroll
                for (int i = 0; i < 4; ++i) {
                    int j = q*4+i;
                    if (h[j] > T) selmask |= (1u << j);
                    else if (h[j] == T) { if (rk < need) selmask |= (1u << j); rk++; }
                }
                base += tot;
            }
        }
        if (T > 0.f) {
            if (cgt_t + ceq_t != TOPK && ceq_t > need) flag = 1;
            else if (T - below < FIX_WINDOW) flag = 1;
        }
        const int myc = __popc(selmask);
        int ip = myc;
#pragma unroll
        for (int d = 1; d < 64; d <<= 1) {
            int o = __shfl_up(ip, d, 64);
            if (lane >= d) ip += o;
        }
        int pos = ip - myc;
        for (int j = 0; j < 32; ++j) {
            if ((selmask >> j) & 1u) {
                int e = (j >> 2) * 256 + lane * 4 + (j & 3);
                IwR[pos] = e;
                VwR[pos] = h[j];
                ldsi[pos] = e;          // mirror (compact order, matches IwR layout)
                ldsv[pos] = h[j];
                pos++;
            }
        }
    }

#pragma unroll
    for (int q = 0; q < 8; ++q) {
        float4 o;
        o.x = ((selmask >> (q*4+0)) & 1u) ? h[q*4+0] : 0.f;
        o.y = ((selmask >> (q*4+1)) & 1u) ? h[q*4+1] : 0.f;
        o.z = ((selmask >> (q*4+2)) & 1u) ? h[q*4+2] : 0.f;
        o.w = ((selmask >> (q*4+3)) & 1u) ? h[q*4+3] : 0.f;
        *(float4*)&row[q * 256 + lane * 4] = o;
    }
    asm volatile("s_waitcnt lgkmcnt(0)" ::: "memory");   // mirror visible to wave
    return flag;
}

// ------- topk (blocks 0..nTopk-1) fused with pack_W (blocks nTopk..nTopk+1023) -------
__global__ __launch_bounds__(256) void topk_packW(
    float* __restrict__ y, const float* __restrict__ g1, const float* __restrict__ b1,
    int* __restrict__ Iw, float* __restrict__ Vw,
    int* __restrict__ flags, int* __restrict__ rowlist, int* __restrict__ cntr,
    const float* __restrict__ Wd, const float* __restrict__ Wb, uint* __restrict__ Wp,
    int nTopk)
{
    __shared__ float ldsv[4][64];
    __shared__ int   ldsi[4][64];
    const int bid = blockIdx.x;
    const int t = threadIdx.x;
    if (bid >= nTopk) {
        const int e = (bid - nTopk) * 2 + (t >> 7);
        const int tt = t & 127;
#pragma unroll
        for (int j = 0; j < 3; ++j) {
            const int c = tt + 128 * j;
            const ushort d = f2bf_hi(Wd[(size_t)e * B_D + c]);
            const ushort b = f2bf_hi(Wb[(size_t)e * B_D + c]);
            Wp[(size_t)e * B_D + c] = ((uint)b << 16) | (uint)d;
        }
        return;
    }
    const int lane = t & 63;
    const int w = t >> 6;
    const int r = bid * 4 + w;
    float* row = y + (size_t)r * B_E;
    float h[32];
#pragma unroll
    for (int q = 0; q < 8; ++q) {
        float4 v = *(const float4*)&row[q * 256 + lane * 4];
        h[q*4+0] = v.x; h[q*4+1] = v.y; h[q*4+2] = v.z; h[q*4+3] = v.w;
    }
    int flag = ln_topk_row(h, lane, g1, b1, row, Iw + r * TOPK, Vw + r * TOPK,
                           ldsv[w], ldsi[w]);
    if (lane == 0) {
        flags[r] = flag;
        if (flag) {
            int p = atomicAdd(cntr, 1);
            rowlist[p] = r;
        }
    }
}

// ------- fixup: exact fp32 recompute of flagged rows (grid-stride batches) -------
// Per-column arithmetic bit-identical: acc = be[c]; fmaf ascending k.
__global__ __launch_bounds__(256) void fixup_recompute(
    const float* __restrict__ x, const float* __restrict__ We, const float* __restrict__ be,
    float* __restrict__ y, const int* __restrict__ rowlist, const int* __restrict__ cntr)
{
    const int nflag = *cntr;
    const int t = threadIdx.x;
    __shared__ float xs[8][B_D];
    __shared__ int   rIdx[8];

    for (int rb = blockIdx.y * 8; rb < nflag; rb += gridDim.y * 8) {
        const int nact = min(nflag - rb, 8);
        __syncthreads();   // protect xs/rIdx reuse across iterations
        if (t < 8) rIdx[t] = (t < nact) ? rowlist[rb + t] : -1;
        __syncthreads();
#pragma unroll
        for (int i = 0; i < 8; ++i) {
            if (i < nact) {
                const float* src = x + (size_t)rIdx[i] * B_D;
                for (int j = t; j < B_D; j += 256) xs[i][j] = src[j];
            } else {
                for (int j = t; j < B_D; j += 256) xs[i][j] = 0.f;
            }
        }
        __syncthreads();

        const int c = blockIdx.x * 256 + t;
        const float bc = be[c];
        float acc[8];
#pragma unroll
        for (int i = 0; i < 8; ++i) acc[i] = bc;
#pragma unroll 4
        for (int k = 0; k < B_D; ++k) {
            const float w = We[(size_t)k * B_E + c];
#pragma unroll
            for (int i = 0; i < 8; ++i) acc[i] = fmaf(xs[i][k], w, acc[i]);
        }
#pragma unroll
        for (int i = 0; i < 8; ++i)
            if (i < nact) y[(size_t)rIdx[i] * B_E + c] = acc[i];
    }
}

// ---- decode (packed bf16 weights), one wave per row; flagged rows first
// redo the exact selection in-wave (replaces fixup_select), then decode. ----
__global__ __launch_bounds__(256) void decode_fused(
    float* __restrict__ y, const float* __restrict__ g1, const float* __restrict__ b1,
    int* __restrict__ Iw, float* __restrict__ Vw, const int* __restrict__ flags,
    const uint* __restrict__ Wp, const float* __restrict__ bd,
    const float* __restrict__ bbias, const float* __restrict__ g2,
    const float* __restrict__ b2, float* __restrict__ recon, float* __restrict__ sep)
{
    __shared__ float ldsv[4][64];
    __shared__ int   ldsi[4][64];
    const int w = threadIdx.x >> 6, lane = threadIdx.x & 63;
    const int r = blockIdx.x * 4 + w;

    int   iv = 0;
    float vv = 0.f;
    if (flags[r]) {
        // inline re-selection on the exact y row (written by fixup_recompute)
        float* row = y + (size_t)r * B_E;
        float h[32];
#pragma unroll
        for (int q = 0; q < 8; ++q) {
            float4 v = *(const float4*)&row[q * 256 + lane * 4];
            h[q*4+0] = v.x; h[q*4+1] = v.y; h[q*4+2] = v.z; h[q*4+3] = v.w;
        }
        ln_topk_row(h, lane, g1, b1, row, Iw + r * TOPK, Vw + r * TOPK,
                    ldsv[w], ldsi[w]);
        iv = ldsi[w][lane];
        vv = ldsv[w][lane];
    } else if (lane < TOPK) {
        iv = Iw[r * TOPK + lane];
        vv = Vw[r * TOPK + lane];
    }

    float ad[6], ab[6];
#pragma unroll
    for (int j = 0; j < 6; ++j) {
        const int c = j * 64 + lane;
        ad[j] = bd[c];
        ab[j] = bbias[c];
    }
#pragma unroll 2
    for (int i = 0; i < TOPK; ++i) {
        const int   idx = __shfl(iv, i, 64);
        const float v   = __shfl(vv, i, 64);
        const uint* wp  = Wp + (size_t)idx * B_D;
#pragma unroll
        for (int j = 0; j < 6; ++j) {
            const uint u = wp[j * 64 + lane];
            const float wd = __uint_as_float(u << 16);
            const float wb = __uint_as_float(u & 0xFFFF0000u);
            ad[j] = fmaf(v, wd, ad[j]);
            ab[j] = fmaf(v, wb, ab[j]);
        }
    }
#pragma unroll
    for (int j = 0; j < 6; ++j) recon[(size_t)r * B_D + j * 64 + lane] = ad[j];
    // LayerNorm over the 384 ab values (single wave owns the row)
    float s = 0.f;
#pragma unroll
    for (int j = 0; j < 6; ++j) s += ab[j];
    s = wave_sum_f(s);
    const float mu = s * (1.f / B_D);
    float ss = 0.f;
#pragma unroll
    for (int j = 0; j < 6; ++j) { float d = ab[j] - mu; ss += d * d; }
    ss = wave_sum_f(ss);
    const float rstd = rsqrtf(ss * (1.f / B_D) + LN_EPS);
#pragma unroll
    for (int j = 0; j < 6; ++j) {
        const int c = j * 64 + lane;
        sep[(size_t)r * B_D + c] = fmaf((ab[j] - mu) * rstd, g2[c], b2[c]);
    }
}

// -------- decode (f32 weights) — fallback only --------
__global__ __launch_bounds__(128) void decode_f32(
    const int* __restrict__ Iw, const float* __restrict__ Vw,
    const float* __restrict__ Wd, const float* __restrict__ bd,
    const float* __restrict__ Wb, const float* __restrict__ bbias,
    const float* __restrict__ g2, const float* __restrict__ b2,
    float* __restrict__ recon, float* __restrict__ sep)
{
    __shared__ int   sI[TOPK];
    __shared__ float sV[TOPK];
    __shared__ float red[2];
    const int r = blockIdx.x, t = threadIdx.x;
    if (t < TOPK) { sI[t] = Iw[r * TOPK + t]; sV[t] = Vw[r * TOPK + t]; }
    __syncthreads();
    float ad[3], ab[3];
#pragma unroll
    for (int j = 0; j < 3; ++j) { ad[j] = bd[t + 128*j]; ab[j] = bbias[t + 128*j]; }
#pragma unroll 2
    for (int i = 0; i < TOPK; ++i) {
        const int   idx = sI[i];
        const float v   = sV[i];
        const float* wd = Wd + (size_t)idx * B_D;
        const float* wb = Wb + (size_t)idx * B_D;
#pragma unroll
        for (int j = 0; j < 3; ++j) {
            ad[j] = fmaf(v, wd[t + 128*j], ad[j]);
            ab[j] = fmaf(v, wb[t + 128*j], ab[j]);
        }
    }
#pragma unroll
    for (int j = 0; j < 3; ++j) recon[(size_t)r * B_D + t + 128*j] = ad[j];
    float s = ab[0] + ab[1] + ab[2];
    s = wave_sum_f(s);
    if ((t & 63) == 0) red[t >> 6] = s;
    __syncthreads();
    const float mu = (red[0] + red[1]) * (1.f / B_D);
    __syncthreads();
    float ss = 0.f;
#pragma unroll
    for (int j = 0; j < 3; ++j) { float d = ab[j] - mu; ss += d * d; }
    ss = wave_sum_f(ss);
    if ((t & 63) == 0) red[t >> 6] = ss;
    __syncthreads();
    const float rstd = rsqrtf((red[0] + red[1]) * (1.f / B_D) + LN_EPS);
#pragma unroll
    for (int j = 0; j < 3; ++j) {
        int c = t + 128*j;
        sep[(size_t)r * B_D + c] = fmaf((ab[j] - mu) * rstd, g2[c], b2[c]);
    }
}

// ------- fallback topk (no fixup machinery) -------
__global__ __launch_bounds__(256) void topk_only(
    float* __restrict__ y, const float* __restrict__ g1, const float* __restrict__ b1,
    int* __restrict__ Iw, float* __restrict__ Vw)
{
    __shared__ float ldsv[4][64];
    __shared__ int   ldsi[4][64];
    const int lane = threadIdx.x & 63;
    const int w = threadIdx.x >> 6;
    const int r = blockIdx.x * 4 + w;
    float* row = y + (size_t)r * B_E;
    float h[32];
#pragma unroll
    for (int q = 0; q < 8; ++q) {
        float4 v = *(const float4*)&row[q * 256 + lane * 4];
        h[q*4+0] = v.x; h[q*4+1] = v.y; h[q*4+2] = v.z; h[q*4+3] = v.w;
    }
    ln_topk_row(h, lane, g1, b1, row, Iw + r * TOPK, Vw + r * TOPK, ldsv[w], ldsi[w]);
}

extern "C" void kernel_launch(void* const* d_in, const int* in_sizes, int n_in,
                              void* d_out, int out_size, void* d_ws, size_t ws_size,
                              hipStream_t stream)
{
    const float* x  = (const float*)d_in[0];
    const float* We = (const float*)d_in[1];
    const float* be = (const float*)d_in[2];
    const float* g1 = (const float*)d_in[3];
    const float* b1 = (const float*)d_in[4];
    const float* Wd = (const float*)d_in[5];
    const float* bd = (const float*)d_in[6];
    const float* Wb = (const float*)d_in[7];
    const float* bb = (const float*)d_in[8];
    const float* g2 = (const float*)d_in[9];
    const float* b2 = (const float*)d_in[10];

    const int Brows = in_sizes[0] / B_D;               // 16384
    float* recon  = (float*)d_out;
    float* sparse = recon + (size_t)Brows * B_D;       // [B,2048]
    float* sep    = sparse + (size_t)Brows * B_E;

    char* ws = (char*)d_ws;
    int*   Iw      = (int*)ws;                         // 3,276,800
    float* Vw      = (float*)(ws + 3276800);           // 3,276,800
    int*   flags   = (int*)(ws + 6553600);             // 65,536
    int*   rowlist = (int*)(ws + 6619136);             // 65,536
    int*   cntr    = (int*)(ws + 6684672);             // 64 (padded)
    const size_t apOff = 6688768;                      // Ap: 25,165,824 (aliased by Wp after enc)
    const size_t bpOff = apOff + (size_t)64 * NKP * 2048 * 16;
    const size_t need  = bpOff + (size_t)8 * NKP * 2048 * 16;    // ~35.0 MB

    if (ws_size >= need) {
        ushort* Ap = (ushort*)(ws + apOff);
        ushort* Bp = (ushort*)(ws + bpOff);
        uint*   Wp = (uint*)(ws + apOff);              // aliases Ap (enc done before pack_W blocks)
        pack_AB<<<dim3(NKP, 72), dim3(256), 0, stream>>>(x, We, Ap, Bp, cntr);
        enc_mfma256b<<<dim3(512), dim3(512), 0, stream>>>(Ap, Bp, be, sparse);
        topk_packW<<<dim3(Brows / 4 + 1024), dim3(256), 0, stream>>>(
            sparse, g1, b1, Iw, Vw, flags, rowlist, cntr, Wd, Wb, Wp, Brows / 4);
        fixup_recompute<<<dim3(8, 64), dim3(256), 0, stream>>>(x, We, be, sparse, rowlist, cntr);
        decode_fused<<<dim3(Brows / 4), dim3(256), 0, stream>>>(
            sparse, g1, b1, Iw, Vw, flags, Wp, bd, bb, g2, b2, recon, sep);
    } else {
        enc_gemm_f32<<<dim3(16, 128), dim3(256), 0, stream>>>(x, We, be, sparse);
        topk_only<<<dim3(Brows / 4), dim3(256), 0, stream>>>(sparse, g1, b1, Iw, Vw);
        decode_f32<<<dim3(Brows), dim3(128), 0, stream>>>(Iw, Vw, Wd, bd, Wb, bb, g2, b2, recon, sep);
    }
}